// Round 4
// baseline (553.501 us; speedup 1.0000x reference)
//
#include <hip/hip_runtime.h>
#include <math.h>

#define N_NODES 50000
#define N_EDGES 800000
#define NUM_GRAPHS_ 128
#define SCAN_NB 98   // ceil(50000/512)
#define PL_BLOCKS 128
#define PL_NODES 391     // ceil(50000/128) nodes per place block

typedef unsigned short u16;
typedef unsigned int u32;
typedef __attribute__((ext_vector_type(8))) short bf16x8;   // 8 bf16 (4 VGPRs)
typedef __attribute__((ext_vector_type(4))) float f32x4;    // 4 fp32

__device__ __forceinline__ float elu_f(float v) {
    return v > 0.f ? v : (__expf(v) - 1.f);
}
__device__ __forceinline__ u16 f2bf(float f) {  // RNE
    u32 u = __float_as_uint(f);
    u += 0x7FFFu + ((u >> 16) & 1u);
    return (u16)(u >> 16);
}
__device__ __forceinline__ float bf2f(u16 h) {
    return __uint_as_float(((u32)h) << 16);
}
__device__ __forceinline__ void bfpair(u32 v, float& lo, float& hi) {
    lo = __uint_as_float(v << 16);
    hi = __uint_as_float(v & 0xFFFF0000u);
}
__device__ __forceinline__ u32 packbf(float lo, float hi) {
    return (u32)f2bf(lo) | ((u32)f2bf(hi) << 16);
}

// ---------------------------------------------------------------------------
// xb = bf16(x); also zeroes the degree-counter array (runs before ew_kernel).
// ---------------------------------------------------------------------------
__global__ void conv_x_kernel(const float* __restrict__ x, u16* __restrict__ xb,
                              int4* __restrict__ deg4) {
    int g = blockIdx.x * blockDim.x + threadIdx.x;
    if (g < N_NODES / 4) deg4[g] = (int4){0, 0, 0, 0};
    float4 v = ((const float4*)x)[g];
    uint2 o;
    o.x = packbf(v.x, v.y);
    o.y = packbf(v.z, v.w);
    ((uint2*)xb)[g] = o;
}

// ---------------------------------------------------------------------------
// coo[e] = {src, ew}; dst16[e] = dst; deg[dst]++ (atomic, L2-resident)
// ew = edge_attr[e,:16] . w_fc1 + b_fc1
// ---------------------------------------------------------------------------
__global__ void ew_kernel(const float* __restrict__ edge_attr,
                          const float* __restrict__ w_fc1,
                          const float* __restrict__ b_fc1,
                          const int* __restrict__ edge_index,
                          int2* __restrict__ coo,
                          u16* __restrict__ dst16,
                          int* __restrict__ deg) {
    int e = blockIdx.x * blockDim.x + threadIdx.x;
    if (e >= N_EDGES) return;
    const float4* ea = (const float4*)(edge_attr + (size_t)e * 16);
    const float4* wf = (const float4*)w_fc1;
    float acc = b_fc1[0];
#pragma unroll
    for (int i = 0; i < 4; i++) {
        float4 a = ea[i], w = wf[i];
        acc += a.x * w.x + a.y * w.y + a.z * w.z + a.w * w.w;
    }
    int2 ent;
    ent.x = edge_index[e];
    ent.y = __float_as_int(acc);
    coo[e] = ent;
    const int d = edge_index[N_EDGES + e];
    dst16[e] = (u16)d;
    atomicAdd(&deg[d], 1);
}

// ---------------------------------------------------------------------------
// Hierarchical exclusive scan of deg -> rowptr[N+1]
// ---------------------------------------------------------------------------
__global__ __launch_bounds__(256) void scan1_kernel(const int* __restrict__ deg,
                                                    int* __restrict__ rowptr,
                                                    int* __restrict__ blk_sums) {
    __shared__ int sh[256];
    const int t = threadIdx.x;
    const int base = blockIdx.x * 512;
    const int i0 = base + 2 * t, i1 = i0 + 1;
    int d0 = 0, d1 = 0;
    if (i0 < N_NODES) d0 = deg[i0];
    if (i1 < N_NODES) d1 = deg[i1];
    const int pair = d0 + d1;
    int v = pair;
    sh[t] = v;
    __syncthreads();
#pragma unroll
    for (int off = 1; off < 256; off <<= 1) {
        int add = (t >= off) ? sh[t - off] : 0;
        __syncthreads();
        v += add;
        sh[t] = v;
        __syncthreads();
    }
    const int excl = v - pair;
    if (i0 < N_NODES) rowptr[i0] = excl;
    if (i1 < N_NODES) rowptr[i1] = excl + d0;
    if (t == 255) blk_sums[blockIdx.x] = v;
}

__global__ __launch_bounds__(128) void scan2_kernel(const int* __restrict__ blk_sums,
                                                    int* __restrict__ blk_offs,
                                                    int* __restrict__ rowptr) {
    __shared__ int sh[128];
    const int t = threadIdx.x;
    const int orig = (t < SCAN_NB) ? blk_sums[t] : 0;
    int v = orig;
    sh[t] = v;
    __syncthreads();
#pragma unroll
    for (int off = 1; off < 128; off <<= 1) {
        int add = (t >= off) ? sh[t - off] : 0;
        __syncthreads();
        v += add;
        sh[t] = v;
        __syncthreads();
    }
    if (t < SCAN_NB) blk_offs[t] = v - orig;
    if (t == 127) rowptr[N_NODES] = v;
}

__global__ void scan3_kernel(int* __restrict__ rowptr,
                             const int* __restrict__ blk_offs) {
    int i = blockIdx.x * blockDim.x + threadIdx.x;
    if (i >= N_NODES) return;
    rowptr[i] += blk_offs[i >> 9];
}

// ---------------------------------------------------------------------------
// CSR placement, single-writer regions: block b OWNS nodes
// [b*PL_NODES, (b+1)*PL_NODES) and scans the full dst16 array (L2-resident,
// vectorized 8 dst/load). All writes to a ~50KB csr region come from ONE
// CU/XCD/L2 -> full-line dirties, write amplification ~1. Edge order within
// a row is nondeterministic (fp32 sum-order rounding only).
// ---------------------------------------------------------------------------
__global__ __launch_bounds__(512) void place_kernel(const u16* __restrict__ dst16,
                                                    const int2* __restrict__ coo,
                                                    const int* __restrict__ rowptr,
                                                    int2* __restrict__ csr) {
    __shared__ int lcur[PL_NODES];
    const int base = blockIdx.x * PL_NODES;
    const int nloc = min(PL_NODES, N_NODES - base);
    for (int i = threadIdx.x; i < nloc; i += 512) lcur[i] = rowptr[base + i];
    __syncthreads();
    const uint4* d8 = (const uint4*)dst16;
    for (int chunk = threadIdx.x; chunk < N_EDGES / 8; chunk += 512) {
        const uint4 v = d8[chunk];
        const int e0 = chunk * 8;
        const u32 w[4] = {v.x, v.y, v.z, v.w};
#pragma unroll
        for (int j = 0; j < 8; j++) {
            const int d = (int)((j & 1) ? (w[j >> 1] >> 16) : (w[j >> 1] & 0xFFFFu));
            const int dl = d - base;
            if ((unsigned)dl < (unsigned)nloc) {
                const int slot = atomicAdd(&lcur[dl], 1);
                csr[slot] = coo[e0 + j];
            }
        }
    }
}

// ---------------------------------------------------------------------------
// Gather aggregation (bf16, fp32 accumulate), one WAVE per node. Layers 0/1.
// Writes s and ch = c*h; layer 0 also emits c.
// ---------------------------------------------------------------------------
template <int DIN, bool WRITE_C>
__global__ __launch_bounds__(256) void gather_kernel(
    const u16* __restrict__ xb, const int* __restrict__ rowptr,
    const int2* __restrict__ csr, u16* __restrict__ sb,
    u16* __restrict__ chb, float* __restrict__ c) {
    constexpr int CG = DIN / 4;
    constexpr int EG = 64 / CG;
    const int gid = blockIdx.x * 256 + threadIdx.x;
    const int node = gid >> 6;
    if (node >= N_NODES) return;
    const int lane = threadIdx.x & 63;
    const int cg = lane & (CG - 1);
    const int eg = lane / CG;
    const int beg = rowptr[node];
    const int end = rowptr[node + 1];
    const uint2* x2 = (const uint2*)xb;

    float a0 = 0.f, a1 = 0.f, a2 = 0.f, a3 = 0.f;
    float b0 = 0.f, b1 = 0.f, b2 = 0.f, b3 = 0.f;
    float wsum = 0.f;

    int p = beg + eg;
    for (; p + EG < end; p += 2 * EG) {
        int2 e0 = csr[p];
        int2 e1 = csr[p + EG];
        float w0 = __int_as_float(e0.y);
        float w1 = __int_as_float(e1.y);
        uint2 v0 = x2[(size_t)e0.x * CG + cg];
        uint2 v1 = x2[(size_t)e1.x * CG + cg];
        float f0, f1, f2, f3, g0, g1, g2, g3;
        bfpair(v0.x, f0, f1); bfpair(v0.y, f2, f3);
        bfpair(v1.x, g0, g1); bfpair(v1.y, g2, g3);
        a0 += w0 * f0; a1 += w0 * f1; a2 += w0 * f2; a3 += w0 * f3;
        b0 += w1 * g0; b1 += w1 * g1; b2 += w1 * g2; b3 += w1 * g3;
        wsum += w0 + w1;
    }
    if (p < end) {
        int2 e0 = csr[p];
        float w0 = __int_as_float(e0.y);
        uint2 v0 = x2[(size_t)e0.x * CG + cg];
        float f0, f1, f2, f3;
        bfpair(v0.x, f0, f1); bfpair(v0.y, f2, f3);
        a0 += w0 * f0; a1 += w0 * f1; a2 += w0 * f2; a3 += w0 * f3;
        wsum += w0;
    }
    a0 += b0; a1 += b1; a2 += b2; a3 += b3;

#pragma unroll
    for (int off = 32; off >= CG; off >>= 1) {
        a0 += __shfl_xor(a0, off);
        a1 += __shfl_xor(a1, off);
        a2 += __shfl_xor(a2, off);
        a3 += __shfl_xor(a3, off);
        wsum += __shfl_xor(wsum, off);
    }

    if (lane < CG) {
        uint2 so;
        so.x = packbf(a0, a1);
        so.y = packbf(a2, a3);
        ((uint2*)sb)[(size_t)node * CG + cg] = so;
        const float cn = WRITE_C ? wsum : c[node];
        uint2 hv = x2[(size_t)node * CG + cg];
        float h0, h1, h2, h3;
        bfpair(hv.x, h0, h1); bfpair(hv.y, h2, h3);
        uint2 co;
        co.x = packbf(cn * h0, cn * h1);
        co.y = packbf(cn * h2, cn * h3);
        ((uint2*)chb)[(size_t)node * CG + cg] = co;
    }
    if (WRITE_C && lane == 0) c[node] = wsum;
}

// ---------------------------------------------------------------------------
// Pack weights into MFMA B-frag layout (bf16).
// L0: [w3;w1;-w2] K=192 DOUT=64 ; L1: same K=192 DOUT=128
// L2: WIDE [w3 | -w2 | w1] K=128 DOUT=192
// ---------------------------------------------------------------------------
__global__ void pack_w_kernel(const float* __restrict__ w3_0, const float* __restrict__ w1_0, const float* __restrict__ w2_0,
                              const float* __restrict__ w3_1, const float* __restrict__ w1_1, const float* __restrict__ w2_1,
                              const float* __restrict__ w3_2, const float* __restrict__ w1_2, const float* __restrict__ w2_2,
                              u16* __restrict__ bp0, u16* __restrict__ bp1, u16* __restrict__ bp2) {
    int t = blockIdx.x * blockDim.x + threadIdx.x;
    if (t >= 7680) return;
    u16 buf[8];
    if (t < 4608) {
        // layers 0/1: K-concatenated [w3;w1;-w2]
        int DIN, DOUT, lid;
        const float *w3, *w1, *w2;
        u16* bp;
        if (t < 1536) { DIN = 64; DOUT = 64;  lid = t;        w3 = w3_0; w1 = w1_0; w2 = w2_0; bp = bp0; }
        else          { DIN = 64; DOUT = 128; lid = t - 1536; w3 = w3_1; w1 = w1_1; w2 = w2_1; bp = bp1; }
        const int NT = DOUT / 16;
        const int lane = lid & 63;
        const int fragid = lid >> 6;
        const int chunk = fragid / NT;
        const int ntile = fragid % NT;
        const int n = ntile * 16 + (lane & 15);
        const int kbase = chunk * 32 + (lane >> 4) * 8;
#pragma unroll
        for (int j = 0; j < 8; j++) {
            int k = kbase + j;
            int region = k / DIN;
            int kk = k - region * DIN;
            float v = (region == 0) ? w3[kk * DOUT + n]
                    : (region == 1) ? w1[kk * DOUT + n]
                                    : -w2[kk * DOUT + n];
            buf[j] = f2bf(v);
        }
        *(bf16x8*)(bp + ((size_t)lid << 3)) = *(bf16x8*)buf;
    } else {
        // layer 2 wide: N-concatenated [w3 | -w2 | w1], K=128, DOUT=192
        const int lid = t - 4608;          // 0..3071
        const int NT = 12;
        const int lane = lid & 63;
        const int fragid = lid >> 6;       // 0..47
        const int chunk = fragid / NT;     // 0..3
        const int ntile = fragid % NT;     // 0..11
        const int n = ntile * 16 + (lane & 15);   // 0..191
        const int kbase = chunk * 32 + (lane >> 4) * 8;  // 0..127
#pragma unroll
        for (int j = 0; j < 8; j++) {
            int k = kbase + j;
            float v = (n < 64)  ? w3_2[k * 64 + n]
                    : (n < 128) ? -w2_2[k * 64 + (n - 64)]
                                : w1_2[k * 64 + (n - 128)];
            buf[j] = f2bf(v);
        }
        *(bf16x8*)(bp2 + ((size_t)lid << 3)) = *(bf16x8*)buf;
    }
}

// ---------------------------------------------------------------------------
// MFMA GEMM (layers 0/1): out = elu( [h|s|ch] @ Bp + b3 + c*b1 )
// ---------------------------------------------------------------------------
template <int DIN, int DOUT>
__global__ __launch_bounds__(256) void gemm_mfma(
    const u16* __restrict__ hb, const u16* __restrict__ sb,
    const u16* __restrict__ chb, const u16* __restrict__ Bp,
    const float* __restrict__ cvec, const float* __restrict__ bias1,
    const float* __restrict__ bias3, u16* __restrict__ outp) {
    constexpr int CH = DIN / 32;
    constexpr int CHUNKS = 3 * CH;
    constexpr int NT = DOUT / 16;
    const int tid = threadIdx.x;
    const int wv = tid >> 6;
    const int lane = tid & 63;
    const int l15 = lane & 15;
    const int q = lane >> 4;
    const int mhalf = wv & 1;
    const int nhalf = wv >> 1;
    const int row_base = blockIdx.x * 64 + mhalf * 32;
    const int nt0 = blockIdx.y * 4 + nhalf * 2;

    const int r0 = min(row_base + l15, N_NODES - 1);
    const int r1 = min(row_base + 16 + l15, N_NODES - 1);
    const int qo = q * 8;

    f32x4 acc00 = {0.f, 0.f, 0.f, 0.f};
    f32x4 acc01 = {0.f, 0.f, 0.f, 0.f};
    f32x4 acc10 = {0.f, 0.f, 0.f, 0.f};
    f32x4 acc11 = {0.f, 0.f, 0.f, 0.f};

#pragma unroll
    for (int chunk = 0; chunk < CHUNKS; chunk++) {
        const int region = chunk / CH;
        const int koff = (chunk - region * CH) * 32 + qo;
        const u16* A = (region == 0) ? hb : (region == 1) ? sb : chb;
        bf16x8 a0 = *(const bf16x8*)(A + (size_t)r0 * DIN + koff);
        bf16x8 a1 = *(const bf16x8*)(A + (size_t)r1 * DIN + koff);
        const u16* bp = Bp + (((size_t)(chunk * NT + nt0) * 64 + lane) << 3);
        bf16x8 bf0 = *(const bf16x8*)bp;
        bf16x8 bf1 = *(const bf16x8*)(bp + 64 * 8);
        acc00 = __builtin_amdgcn_mfma_f32_16x16x32_bf16(a0, bf0, acc00, 0, 0, 0);
        acc01 = __builtin_amdgcn_mfma_f32_16x16x32_bf16(a0, bf1, acc01, 0, 0, 0);
        acc10 = __builtin_amdgcn_mfma_f32_16x16x32_bf16(a1, bf0, acc10, 0, 0, 0);
        acc11 = __builtin_amdgcn_mfma_f32_16x16x32_bf16(a1, bf1, acc11, 0, 0, 0);
    }

#pragma unroll
    for (int ni = 0; ni < 2; ni++) {
        const int col = (nt0 + ni) * 16 + l15;
        const float B3 = bias3[col];
        const float B1 = bias1[col];
        const f32x4 am0 = ni ? acc01 : acc00;
        const f32x4 am1 = ni ? acc11 : acc10;
#pragma unroll
        for (int mi = 0; mi < 2; mi++) {
            const f32x4 av = mi ? am1 : am0;
#pragma unroll
            for (int reg = 0; reg < 4; reg++) {
                const int row = row_base + mi * 16 + q * 4 + reg;
                if (row < N_NODES) {
                    const float cv = cvec[row];
                    const float val = av[reg] + B3 + cv * B1;
                    outp[(size_t)row * DOUT + col] = f2bf(elu_f(val));
                }
            }
        }
    }
}

// ---------------------------------------------------------------------------
// Layer-2 wide GEMM: zuy = h2 @ [w3 | -w2 | w1]  (K=128, DOUT=192, no epi)
// ---------------------------------------------------------------------------
__global__ __launch_bounds__(256) void gemm_wide_kernel(
    const u16* __restrict__ hb, const u16* __restrict__ Bp,
    u16* __restrict__ zuy) {
    constexpr int NT = 12;
    const int tid = threadIdx.x;
    const int wv = tid >> 6;
    const int lane = tid & 63;
    const int l15 = lane & 15;
    const int q = lane >> 4;
    const int row_base = blockIdx.x * 64 + (wv & 1) * 32;
    const int nt0 = blockIdx.y * 4 + (wv >> 1) * 2;

    const int r0 = min(row_base + l15, N_NODES - 1);
    const int r1 = min(row_base + 16 + l15, N_NODES - 1);
    const int qo = q * 8;

    f32x4 acc00 = {0.f, 0.f, 0.f, 0.f};
    f32x4 acc01 = {0.f, 0.f, 0.f, 0.f};
    f32x4 acc10 = {0.f, 0.f, 0.f, 0.f};
    f32x4 acc11 = {0.f, 0.f, 0.f, 0.f};

#pragma unroll
    for (int chunk = 0; chunk < 4; chunk++) {
        const int koff = chunk * 32 + qo;
        bf16x8 a0 = *(const bf16x8*)(hb + (size_t)r0 * 128 + koff);
        bf16x8 a1 = *(const bf16x8*)(hb + (size_t)r1 * 128 + koff);
        const u16* bp = Bp + (((size_t)(chunk * NT + nt0) * 64 + lane) << 3);
        bf16x8 bf0 = *(const bf16x8*)bp;
        bf16x8 bf1 = *(const bf16x8*)(bp + 64 * 8);
        acc00 = __builtin_amdgcn_mfma_f32_16x16x32_bf16(a0, bf0, acc00, 0, 0, 0);
        acc01 = __builtin_amdgcn_mfma_f32_16x16x32_bf16(a0, bf1, acc01, 0, 0, 0);
        acc10 = __builtin_amdgcn_mfma_f32_16x16x32_bf16(a1, bf0, acc10, 0, 0, 0);
        acc11 = __builtin_amdgcn_mfma_f32_16x16x32_bf16(a1, bf1, acc11, 0, 0, 0);
    }

#pragma unroll
    for (int ni = 0; ni < 2; ni++) {
        const int col = (nt0 + ni) * 16 + l15;
        const f32x4 am0 = ni ? acc01 : acc00;
        const f32x4 am1 = ni ? acc11 : acc10;
#pragma unroll
        for (int mi = 0; mi < 2; mi++) {
            const f32x4 av = mi ? am1 : am0;
#pragma unroll
            for (int reg = 0; reg < 4; reg++) {
                const int row = row_base + mi * 16 + q * 4 + reg;
                if (row < N_NODES)
                    zuy[(size_t)row * 192 + col] = f2bf(av[reg]);
            }
        }
    }
}

// ---------------------------------------------------------------------------
// Layer-2 gather + fused epilogue. zuy rows: [z(64) | u(64) | y(64)].
// h3[i] = elu( z_i + c_i*u_i + sum_e w_e * y[src_e] + b3 + c_i*b1 )
// ---------------------------------------------------------------------------
__global__ __launch_bounds__(256) void gather2_kernel(
    const u16* __restrict__ zuy, const int* __restrict__ rowptr,
    const int2* __restrict__ csr, const float* __restrict__ c,
    const float* __restrict__ bias1, const float* __restrict__ bias3,
    u16* __restrict__ h3) {
    constexpr int CG = 16, EG = 4;
    const int gid = blockIdx.x * 256 + threadIdx.x;
    const int node = gid >> 6;
    if (node >= N_NODES) return;
    const int lane = threadIdx.x & 63;
    const int cg = lane & (CG - 1);
    const int eg = lane >> 4;
    const int beg = rowptr[node];
    const int end = rowptr[node + 1];

    float a0 = 0.f, a1 = 0.f, a2 = 0.f, a3 = 0.f;
    float b0 = 0.f, b1 = 0.f, b2 = 0.f, b3 = 0.f;

    int p = beg + eg;
    for (; p + EG < end; p += 2 * EG) {
        int2 e0 = csr[p];
        int2 e1 = csr[p + EG];
        float w0 = __int_as_float(e0.y);
        float w1 = __int_as_float(e1.y);
        uint2 v0 = ((const uint2*)(zuy + (size_t)e0.x * 192 + 128))[cg];
        uint2 v1 = ((const uint2*)(zuy + (size_t)e1.x * 192 + 128))[cg];
        float f0, f1, f2, f3, g0, g1, g2, g3;
        bfpair(v0.x, f0, f1); bfpair(v0.y, f2, f3);
        bfpair(v1.x, g0, g1); bfpair(v1.y, g2, g3);
        a0 += w0 * f0; a1 += w0 * f1; a2 += w0 * f2; a3 += w0 * f3;
        b0 += w1 * g0; b1 += w1 * g1; b2 += w1 * g2; b3 += w1 * g3;
    }
    if (p < end) {
        int2 e0 = csr[p];
        float w0 = __int_as_float(e0.y);
        uint2 v0 = ((const uint2*)(zuy + (size_t)e0.x * 192 + 128))[cg];
        float f0, f1, f2, f3;
        bfpair(v0.x, f0, f1); bfpair(v0.y, f2, f3);
        a0 += w0 * f0; a1 += w0 * f1; a2 += w0 * f2; a3 += w0 * f3;
    }
    a0 += b0; a1 += b1; a2 += b2; a3 += b3;

#pragma unroll
    for (int off = 32; off >= CG; off >>= 1) {
        a0 += __shfl_xor(a0, off);
        a1 += __shfl_xor(a1, off);
        a2 += __shfl_xor(a2, off);
        a3 += __shfl_xor(a3, off);
    }

    if (lane < CG) {
        const float cn = c[node];
        const u16* zr = zuy + (size_t)node * 192;
        uint2 zv = ((const uint2*)zr)[cg];
        uint2 uv = ((const uint2*)(zr + 64))[cg];
        float z0, z1, z2, z3, u0, u1, u2, u3;
        bfpair(zv.x, z0, z1); bfpair(zv.y, z2, z3);
        bfpair(uv.x, u0, u1); bfpair(uv.y, u2, u3);
        const float4 b3v = *(const float4*)(bias3 + cg * 4);
        const float4 b1v = *(const float4*)(bias1 + cg * 4);
        float o0 = elu_f(z0 + cn * u0 + a0 + b3v.x + cn * b1v.x);
        float o1 = elu_f(z1 + cn * u1 + a1 + b3v.y + cn * b1v.y);
        float o2 = elu_f(z2 + cn * u2 + a2 + b3v.z + cn * b1v.z);
        float o3 = elu_f(z3 + cn * u3 + a3 + b3v.w + cn * b1v.w);
        uint2 o;
        o.x = packbf(o0, o1);
        o.y = packbf(o2, o3);
        ((uint2*)h3)[(size_t)node * CG + cg] = o;
    }
}

// ---------------------------------------------------------------------------
// out[g, :] = max over nodes of graph g of h[:, :64] (bf16 in, fp32 out)
// ---------------------------------------------------------------------------
__global__ void pool_kernel(const u16* __restrict__ h,
                            const int* __restrict__ batch,
                            float* __restrict__ out) {
    const int g = blockIdx.x;
    const int tid = threadIdx.x;
    int lo = 0, hi = N_NODES;
    while (lo < hi) { int mid = (lo + hi) >> 1; if (batch[mid] < g) lo = mid + 1; else hi = mid; }
    const int beg = lo;
    lo = beg; hi = N_NODES;
    while (lo < hi) { int mid = (lo + hi) >> 1; if (batch[mid] < g + 1) lo = mid + 1; else hi = mid; }
    const int end = lo;

    __shared__ float red[256];
    const int col = tid & 63;
    const int rg = tid >> 6;
    float m = -3.0e38f;
    for (int r = beg + rg; r < end; r += 4) m = fmaxf(m, bf2f(h[(size_t)r * 64 + col]));
    red[tid] = m;
    __syncthreads();
    if (tid < 64) {
        m = fmaxf(fmaxf(red[tid], red[tid + 64]), fmaxf(red[tid + 128], red[tid + 192]));
        out[g * 64 + tid] = m;
    }
}

extern "C" void kernel_launch(void* const* d_in, const int* in_sizes, int n_in,
                              void* d_out, int out_size, void* d_ws, size_t ws_size,
                              hipStream_t stream) {
    const float* x = (const float*)d_in[0];
    const int* ei = (const int*)d_in[1];
    const float* ea = (const float*)d_in[2];
    const int* batch = (const int*)d_in[3];
    const float* wfc = (const float*)d_in[4];
    const float* bfc = (const float*)d_in[5];
    const float* w1_0 = (const float*)d_in[6];
    const float* b1_0 = (const float*)d_in[7];
    const float* w2_0 = (const float*)d_in[8];
    const float* w3_0 = (const float*)d_in[9];
    const float* b3_0 = (const float*)d_in[10];
    const float* w1_1 = (const float*)d_in[11];
    const float* b1_1 = (const float*)d_in[12];
    const float* w2_1 = (const float*)d_in[13];
    const float* w3_1 = (const float*)d_in[14];
    const float* b3_1 = (const float*)d_in[15];
    const float* w1_2 = (const float*)d_in[16];
    const float* b1_2 = (const float*)d_in[17];
    const float* w2_2 = (const float*)d_in[18];
    const float* w3_2 = (const float*)d_in[19];
    const float* b3_2 = (const float*)d_in[20];
    float* out = (float*)d_out;

    char* ws = (char*)d_ws;
    int2*  coo     = (int2*) (ws);                 // E int2     6.4 MB
    u16*   dst16   = (u16*)  (ws + 6400000);       // E u16      1.6 MB
    float* c       = (float*)(ws + 8000000);       // N f32
    int*   rowptr  = (int*)  (ws + 8200000);       // N+1 int
    int2*  csr     = (int2*) (ws + 8400128);       // E int2     6.4 MB
    u16*   xb      = (u16*)  (ws + 14800128);      // N*64 bf16  6.4 MB
    u16*   sb      = (u16*)  (ws + 21200128);      // N*128 bf16 12.8 MB
    u16*   chb     = (u16*)  (ws + 34000128);      // N*128 bf16 12.8 MB
    u16*   h1      = (u16*)  (ws + 46800128);      // N*64 bf16  6.4 MB
    u16*   h2      = (u16*)  (ws + 53200128);      // N*128 bf16 12.8 MB
    u16*   bp0     = (u16*)  (ws + 66000128);      // 24 KB packed weights L0
    u16*   bp1     = (u16*)  (ws + 66024704);      // 48 KB L1
    u16*   bp2     = (u16*)  (ws + 66073856);      // 48 KB L2 wide
    int*   deg     = (int*)  (ws + 66123008);      // N int (16B aligned)
    int* blk_sums  = (int*)  (ws + 66323008);
    int* blk_offs  = (int*)  (ws + 66323520);
    // aliases into regions dead at time of use:
    u16* zuy = sb;   // N*192 bf16 = 19.2 MB over sb+chb (dead after gemm L1)
    u16* h3  = xb;   // N*64 bf16 (xb dead after layer-0 gemm)

    // --- CSR build: atomic degree count + hierarchical scan + single-writer place
    conv_x_kernel<<<3125, 256, 0, stream>>>(x, xb, (int4*)deg);
    ew_kernel<<<3125, 256, 0, stream>>>(ea, wfc, bfc, ei, coo, dst16, deg);
    pack_w_kernel<<<30, 256, 0, stream>>>(w3_0, w1_0, w2_0, w3_1, w1_1, w2_1,
                                          w3_2, w1_2, w2_2, bp0, bp1, bp2);
    scan1_kernel<<<SCAN_NB, 256, 0, stream>>>(deg, rowptr, blk_sums);
    scan2_kernel<<<1, 128, 0, stream>>>(blk_sums, blk_offs, rowptr);
    scan3_kernel<<<(N_NODES + 255) / 256, 256, 0, stream>>>(rowptr, blk_offs);
    place_kernel<<<PL_BLOCKS, 512, 0, stream>>>(dst16, coo, rowptr, csr);

    const int RB = (N_NODES + 63) / 64;           // 782 row-blocks
    const int GBLK = (N_NODES * 64 + 255) / 256;  // one wave per node

    // layer 0: 64 -> 64
    gather_kernel<64, true><<<GBLK, 256, 0, stream>>>(xb, rowptr, csr, sb, chb, c);
    gemm_mfma<64, 64><<<dim3(RB, 1), 256, 0, stream>>>(xb, sb, chb, bp0, c, b1_0, b3_0, h1);

    // layer 1: 64 -> 128
    gather_kernel<64, false><<<GBLK, 256, 0, stream>>>(h1, rowptr, csr, sb, chb, c);
    gemm_mfma<64, 128><<<dim3(RB, 2), 256, 0, stream>>>(h1, sb, chb, bp1, c, b1_1, b3_1, h2);

    // layer 2: 128 -> 64, restructured: wide gemm then output-space gather
    gemm_wide_kernel<<<dim3(RB, 3), 256, 0, stream>>>(h2, bp2, zuy);
    gather2_kernel<<<GBLK, 256, 0, stream>>>(zuy, rowptr, csr, c, b1_2, b3_2, h3);

    // global max pool
    pool_kernel<<<NUM_GRAPHS_, 256, 0, stream>>>(h3, batch, out);
}

// Round 5
// 337.457 us; speedup vs baseline: 1.6402x; 1.6402x over previous
//
#include <hip/hip_runtime.h>
#include <math.h>

#define N_NODES 50000
#define N_EDGES 800000
#define NUM_GRAPHS_ 128
#define SCAN_NB 98   // ceil(50000/512)
#define NPASS 8
#define NODES_PER_PASS 6250  // 50000/8
#define HCHUNKS 128
#define EDGES_PER_CHUNK 6250 // 800000/128
#define HWORDS 12500         // 25000 nodes per half, 2 per word

typedef unsigned short u16;
typedef unsigned int u32;
typedef __attribute__((ext_vector_type(8))) short bf16x8;   // 8 bf16 (4 VGPRs)
typedef __attribute__((ext_vector_type(4))) float f32x4;    // 4 fp32

__device__ __forceinline__ float elu_f(float v) {
    return v > 0.f ? v : (__expf(v) - 1.f);
}
__device__ __forceinline__ u16 f2bf(float f) {  // RNE
    u32 u = __float_as_uint(f);
    u += 0x7FFFu + ((u >> 16) & 1u);
    return (u16)(u >> 16);
}
__device__ __forceinline__ float bf2f(u16 h) {
    return __uint_as_float(((u32)h) << 16);
}
__device__ __forceinline__ void bfpair(u32 v, float& lo, float& hi) {
    lo = __uint_as_float(v << 16);
    hi = __uint_as_float(v & 0xFFFF0000u);
}
__device__ __forceinline__ u32 packbf(float lo, float hi) {
    return (u32)f2bf(lo) | ((u32)f2bf(hi) << 16);
}

// ---------------------------------------------------------------------------
// xb = bf16(x)
// ---------------------------------------------------------------------------
__global__ void conv_x_kernel(const float* __restrict__ x, u16* __restrict__ xb) {
    int g = blockIdx.x * blockDim.x + threadIdx.x;
    float4 v = ((const float4*)x)[g];
    uint2 o;
    o.x = packbf(v.x, v.y);
    o.y = packbf(v.z, v.w);
    ((uint2*)xb)[g] = o;
}

// ---------------------------------------------------------------------------
// ew[e] = edge_attr[e,:16] . w_fc1 + b_fc1 ; dst16[e] = dst.  NO atomics.
// ---------------------------------------------------------------------------
__global__ void ew_kernel(const float* __restrict__ edge_attr,
                          const float* __restrict__ w_fc1,
                          const float* __restrict__ b_fc1,
                          const int* __restrict__ edge_index,
                          float* __restrict__ ew,
                          u16* __restrict__ dst16) {
    int e = blockIdx.x * blockDim.x + threadIdx.x;
    if (e >= N_EDGES) return;
    const float4* ea = (const float4*)(edge_attr + (size_t)e * 16);
    const float4* wf = (const float4*)w_fc1;
    float acc = b_fc1[0];
#pragma unroll
    for (int i = 0; i < 4; i++) {
        float4 a = ea[i], w = wf[i];
        acc += a.x * w.x + a.y * w.y + a.z * w.z + a.w * w.w;
    }
    ew[e] = acc;
    dst16[e] = (u16)edge_index[N_EDGES + e];
}

// ---------------------------------------------------------------------------
// Degree histogram per (chunk, half): LDS atomics only, dense write.
// ---------------------------------------------------------------------------
__global__ __launch_bounds__(256) void deg_hist_kernel(const u16* __restrict__ dst16,
                                                       u32* __restrict__ partial) {
    __shared__ u32 bins[HWORDS];
    const int c = blockIdx.x >> 1;
    const int p = blockIdx.x & 1;
    const int t = threadIdx.x;
    for (int i = t; i < HWORDS; i += 256) bins[i] = 0;
    __syncthreads();
    const int base = c * EDGES_PER_CHUNK;
    const int nlo = p * 25000;
    for (int i = t; i < EDGES_PER_CHUNK; i += 256) {
        const int b = (int)dst16[base + i] - nlo;
        if ((unsigned)b < 25000u)
            atomicAdd(&bins[b >> 1], 1u << ((b & 1) * 16));
    }
    __syncthreads();
    u32* outp = partial + (size_t)blockIdx.x * HWORDS;
    for (int i = t; i < HWORDS; i += 256) outp[i] = bins[i];
}

// ---------------------------------------------------------------------------
// Exclusive scan along the chunk axis: prefpack[c][node-pair] = count of this
// node's edges in chunks < c (packed u16 pair). degpack = total (= degree).
// ---------------------------------------------------------------------------
__global__ __launch_bounds__(256) void scan_chunks_kernel(const u32* __restrict__ partial,
                                                          u32* __restrict__ prefpack,
                                                          u32* __restrict__ degpack) {
    const int g = blockIdx.x * 256 + threadIdx.x;  // node-pair index 0..24999
    if (g >= 25000) return;
    const int p = (g >= HWORDS) ? 1 : 0;
    const int wh = g - p * HWORDS;
    u32 runlo = 0, runhi = 0;
    for (int c = 0; c < HCHUNKS; c++) {
        prefpack[(size_t)c * 25000 + g] = runlo | (runhi << 16);
        u32 v = partial[(size_t)((c << 1) + p) * HWORDS + wh];
        runlo += v & 0xFFFFu;
        runhi += v >> 16;
    }
    degpack[g] = runlo | (runhi << 16);
}

// ---------------------------------------------------------------------------
// Hierarchical exclusive scan of degpack -> rowptr[N+1]
// ---------------------------------------------------------------------------
__global__ __launch_bounds__(256) void scan1_kernel(const u32* __restrict__ degpack,
                                                    int* __restrict__ rowptr,
                                                    int* __restrict__ blk_sums) {
    __shared__ int sh[256];
    const int t = threadIdx.x;
    const int base = blockIdx.x * 512;
    const int i0 = base + 2 * t, i1 = i0 + 1;
    int d0 = 0, d1 = 0;
    if (i0 < N_NODES) {
        u32 v = degpack[i0 >> 1];
        d0 = (int)(v & 0xFFFFu);
        d1 = (int)(v >> 16);
    }
    const int pair = d0 + d1;
    int v = pair;
    sh[t] = v;
    __syncthreads();
#pragma unroll
    for (int off = 1; off < 256; off <<= 1) {
        int add = (t >= off) ? sh[t - off] : 0;
        __syncthreads();
        v += add;
        sh[t] = v;
        __syncthreads();
    }
    const int excl = v - pair;
    if (i0 < N_NODES) rowptr[i0] = excl;
    if (i1 < N_NODES) rowptr[i1] = excl + d0;
    if (t == 255) blk_sums[blockIdx.x] = v;
}

__global__ __launch_bounds__(128) void scan2_kernel(const int* __restrict__ blk_sums,
                                                    int* __restrict__ blk_offs,
                                                    int* __restrict__ rowptr) {
    __shared__ int sh[128];
    const int t = threadIdx.x;
    const int orig = (t < SCAN_NB) ? blk_sums[t] : 0;
    int v = orig;
    sh[t] = v;
    __syncthreads();
#pragma unroll
    for (int off = 1; off < 128; off <<= 1) {
        int add = (t >= off) ? sh[t - off] : 0;
        __syncthreads();
        v += add;
        sh[t] = v;
        __syncthreads();
    }
    if (t < SCAN_NB) blk_offs[t] = v - orig;
    if (t == 127) rowptr[N_NODES] = v;
}

__global__ void scan3_kernel(int* __restrict__ rowptr,
                             const int* __restrict__ blk_offs) {
    int i = blockIdx.x * blockDim.x + threadIdx.x;
    if (i >= N_NODES) return;
    rowptr[i] += blk_offs[i >> 9];
}

// ---------------------------------------------------------------------------
// CSR placement, NO global atomics (counting sort).
// Block (chunk c, pass p): slot = rowptr[d] + prefpack[c][d] + LDS local rank.
// pass = blockIdx&7 keeps each pass's 800KB csr region on one XCD.
// ---------------------------------------------------------------------------
__global__ __launch_bounds__(256) void place_kernel(const int* __restrict__ edge_index,
                                                    const float* __restrict__ ew,
                                                    const u16* __restrict__ dst16,
                                                    const int* __restrict__ rowptr,
                                                    const u32* __restrict__ prefpack,
                                                    int2* __restrict__ csr) {
    __shared__ int lcur[NODES_PER_PASS];
    const int pass = blockIdx.x & (NPASS - 1);
    const int c = blockIdx.x >> 3;
    const int lo = pass * NODES_PER_PASS;
    const int t = threadIdx.x;
    for (int i = t; i < NODES_PER_PASS; i += 256) lcur[i] = 0;
    __syncthreads();
    const int base = c * EDGES_PER_CHUNK;
    for (int i = t; i < EDGES_PER_CHUNK; i += 256) {
        const int e = base + i;
        const int d = (int)dst16[e];
        const int dl = d - lo;
        if ((unsigned)dl < (unsigned)NODES_PER_PASS) {
            u32 pw = prefpack[(size_t)c * 25000 + (d >> 1)];
            int pref = (int)((pw >> ((d & 1) * 16)) & 0xFFFFu);
            int lpos = atomicAdd(&lcur[dl], 1);
            int2 ent;
            ent.x = edge_index[e];
            ent.y = __float_as_int(ew[e]);
            csr[rowptr[d] + pref + lpos] = ent;
        }
    }
}

// ---------------------------------------------------------------------------
// Gather aggregation (bf16, fp32 accumulate), one WAVE per node. Layers 0/1.
// Writes s and ch = c*h; layer 0 also emits c.
// ---------------------------------------------------------------------------
template <int DIN, bool WRITE_C>
__global__ __launch_bounds__(256) void gather_kernel(
    const u16* __restrict__ xb, const int* __restrict__ rowptr,
    const int2* __restrict__ csr, u16* __restrict__ sb,
    u16* __restrict__ chb, float* __restrict__ c) {
    constexpr int CG = DIN / 4;
    constexpr int EG = 64 / CG;
    const int gid = blockIdx.x * 256 + threadIdx.x;
    const int node = gid >> 6;
    if (node >= N_NODES) return;
    const int lane = threadIdx.x & 63;
    const int cg = lane & (CG - 1);
    const int eg = lane / CG;
    const int beg = rowptr[node];
    const int end = rowptr[node + 1];
    const uint2* x2 = (const uint2*)xb;

    float a0 = 0.f, a1 = 0.f, a2 = 0.f, a3 = 0.f;
    float b0 = 0.f, b1 = 0.f, b2 = 0.f, b3 = 0.f;
    float wsum = 0.f;

    int p = beg + eg;
    for (; p + EG < end; p += 2 * EG) {
        int2 e0 = csr[p];
        int2 e1 = csr[p + EG];
        float w0 = __int_as_float(e0.y);
        float w1 = __int_as_float(e1.y);
        uint2 v0 = x2[(size_t)e0.x * CG + cg];
        uint2 v1 = x2[(size_t)e1.x * CG + cg];
        float f0, f1, f2, f3, g0, g1, g2, g3;
        bfpair(v0.x, f0, f1); bfpair(v0.y, f2, f3);
        bfpair(v1.x, g0, g1); bfpair(v1.y, g2, g3);
        a0 += w0 * f0; a1 += w0 * f1; a2 += w0 * f2; a3 += w0 * f3;
        b0 += w1 * g0; b1 += w1 * g1; b2 += w1 * g2; b3 += w1 * g3;
        wsum += w0 + w1;
    }
    if (p < end) {
        int2 e0 = csr[p];
        float w0 = __int_as_float(e0.y);
        uint2 v0 = x2[(size_t)e0.x * CG + cg];
        float f0, f1, f2, f3;
        bfpair(v0.x, f0, f1); bfpair(v0.y, f2, f3);
        a0 += w0 * f0; a1 += w0 * f1; a2 += w0 * f2; a3 += w0 * f3;
        wsum += w0;
    }
    a0 += b0; a1 += b1; a2 += b2; a3 += b3;

#pragma unroll
    for (int off = 32; off >= CG; off >>= 1) {
        a0 += __shfl_xor(a0, off);
        a1 += __shfl_xor(a1, off);
        a2 += __shfl_xor(a2, off);
        a3 += __shfl_xor(a3, off);
        wsum += __shfl_xor(wsum, off);
    }

    if (lane < CG) {
        uint2 so;
        so.x = packbf(a0, a1);
        so.y = packbf(a2, a3);
        ((uint2*)sb)[(size_t)node * CG + cg] = so;
        const float cn = WRITE_C ? wsum : c[node];
        uint2 hv = x2[(size_t)node * CG + cg];
        float h0, h1, h2, h3;
        bfpair(hv.x, h0, h1); bfpair(hv.y, h2, h3);
        uint2 co;
        co.x = packbf(cn * h0, cn * h1);
        co.y = packbf(cn * h2, cn * h3);
        ((uint2*)chb)[(size_t)node * CG + cg] = co;
    }
    if (WRITE_C && lane == 0) c[node] = wsum;
}

// ---------------------------------------------------------------------------
// Pack weights into MFMA B-frag layout (bf16).
// L0: [w3;w1;-w2] K=192 DOUT=64 ; L1: same K=192 DOUT=128
// L2: WIDE [w3 | -w2 | w1] K=128 DOUT=192
// ---------------------------------------------------------------------------
__global__ void pack_w_kernel(const float* __restrict__ w3_0, const float* __restrict__ w1_0, const float* __restrict__ w2_0,
                              const float* __restrict__ w3_1, const float* __restrict__ w1_1, const float* __restrict__ w2_1,
                              const float* __restrict__ w3_2, const float* __restrict__ w1_2, const float* __restrict__ w2_2,
                              u16* __restrict__ bp0, u16* __restrict__ bp1, u16* __restrict__ bp2) {
    int t = blockIdx.x * blockDim.x + threadIdx.x;
    if (t >= 7680) return;
    u16 buf[8];
    if (t < 4608) {
        // layers 0/1: K-concatenated [w3;w1;-w2]
        int DIN, DOUT, lid;
        const float *w3, *w1, *w2;
        u16* bp;
        if (t < 1536) { DIN = 64; DOUT = 64;  lid = t;        w3 = w3_0; w1 = w1_0; w2 = w2_0; bp = bp0; }
        else          { DIN = 64; DOUT = 128; lid = t - 1536; w3 = w3_1; w1 = w1_1; w2 = w2_1; bp = bp1; }
        const int NT = DOUT / 16;
        const int lane = lid & 63;
        const int fragid = lid >> 6;
        const int chunk = fragid / NT;
        const int ntile = fragid % NT;
        const int n = ntile * 16 + (lane & 15);
        const int kbase = chunk * 32 + (lane >> 4) * 8;
#pragma unroll
        for (int j = 0; j < 8; j++) {
            int k = kbase + j;
            int region = k / DIN;
            int kk = k - region * DIN;
            float v = (region == 0) ? w3[kk * DOUT + n]
                    : (region == 1) ? w1[kk * DOUT + n]
                                    : -w2[kk * DOUT + n];
            buf[j] = f2bf(v);
        }
        *(bf16x8*)(bp + ((size_t)lid << 3)) = *(bf16x8*)buf;
    } else {
        // layer 2 wide: N-concatenated [w3 | -w2 | w1], K=128, DOUT=192
        const int lid = t - 4608;          // 0..3071
        const int NT = 12;
        const int lane = lid & 63;
        const int fragid = lid >> 6;       // 0..47
        const int chunk = fragid / NT;     // 0..3
        const int ntile = fragid % NT;     // 0..11
        const int n = ntile * 16 + (lane & 15);   // 0..191
        const int kbase = chunk * 32 + (lane >> 4) * 8;  // 0..127
#pragma unroll
        for (int j = 0; j < 8; j++) {
            int k = kbase + j;
            float v = (n < 64)  ? w3_2[k * 64 + n]
                    : (n < 128) ? -w2_2[k * 64 + (n - 64)]
                                : w1_2[k * 64 + (n - 128)];
            buf[j] = f2bf(v);
        }
        *(bf16x8*)(bp2 + ((size_t)lid << 3)) = *(bf16x8*)buf;
    }
}

// ---------------------------------------------------------------------------
// MFMA GEMM (layer 0): out = elu( [h|s|ch] @ Bp + b3 + c*b1 )
// ---------------------------------------------------------------------------
template <int DIN, int DOUT>
__global__ __launch_bounds__(256) void gemm_mfma(
    const u16* __restrict__ hb, const u16* __restrict__ sb,
    const u16* __restrict__ chb, const u16* __restrict__ Bp,
    const float* __restrict__ cvec, const float* __restrict__ bias1,
    const float* __restrict__ bias3, u16* __restrict__ outp) {
    constexpr int CH = DIN / 32;
    constexpr int CHUNKS = 3 * CH;
    constexpr int NT = DOUT / 16;
    const int tid = threadIdx.x;
    const int wv = tid >> 6;
    const int lane = tid & 63;
    const int l15 = lane & 15;
    const int q = lane >> 4;
    const int mhalf = wv & 1;
    const int nhalf = wv >> 1;
    const int row_base = blockIdx.x * 64 + mhalf * 32;
    const int nt0 = blockIdx.y * 4 + nhalf * 2;

    const int r0 = min(row_base + l15, N_NODES - 1);
    const int r1 = min(row_base + 16 + l15, N_NODES - 1);
    const int qo = q * 8;

    f32x4 acc00 = {0.f, 0.f, 0.f, 0.f};
    f32x4 acc01 = {0.f, 0.f, 0.f, 0.f};
    f32x4 acc10 = {0.f, 0.f, 0.f, 0.f};
    f32x4 acc11 = {0.f, 0.f, 0.f, 0.f};

#pragma unroll
    for (int chunk = 0; chunk < CHUNKS; chunk++) {
        const int region = chunk / CH;
        const int koff = (chunk - region * CH) * 32 + qo;
        const u16* A = (region == 0) ? hb : (region == 1) ? sb : chb;
        bf16x8 a0 = *(const bf16x8*)(A + (size_t)r0 * DIN + koff);
        bf16x8 a1 = *(const bf16x8*)(A + (size_t)r1 * DIN + koff);
        const u16* bp = Bp + (((size_t)(chunk * NT + nt0) * 64 + lane) << 3);
        bf16x8 bf0 = *(const bf16x8*)bp;
        bf16x8 bf1 = *(const bf16x8*)(bp + 64 * 8);
        acc00 = __builtin_amdgcn_mfma_f32_16x16x32_bf16(a0, bf0, acc00, 0, 0, 0);
        acc01 = __builtin_amdgcn_mfma_f32_16x16x32_bf16(a0, bf1, acc01, 0, 0, 0);
        acc10 = __builtin_amdgcn_mfma_f32_16x16x32_bf16(a1, bf0, acc10, 0, 0, 0);
        acc11 = __builtin_amdgcn_mfma_f32_16x16x32_bf16(a1, bf1, acc11, 0, 0, 0);
    }

#pragma unroll
    for (int ni = 0; ni < 2; ni++) {
        const int col = (nt0 + ni) * 16 + l15;
        const float B3 = bias3[col];
        const float B1 = bias1[col];
        const f32x4 am0 = ni ? acc01 : acc00;
        const f32x4 am1 = ni ? acc11 : acc10;
#pragma unroll
        for (int mi = 0; mi < 2; mi++) {
            const f32x4 av = mi ? am1 : am0;
#pragma unroll
            for (int reg = 0; reg < 4; reg++) {
                const int row = row_base + mi * 16 + q * 4 + reg;
                if (row < N_NODES) {
                    const float cv = cvec[row];
                    const float val = av[reg] + B3 + cv * B1;
                    outp[(size_t)row * DOUT + col] = f2bf(elu_f(val));
                }
            }
        }
    }
}

// ---------------------------------------------------------------------------
// FUSED layer-1 GEMM + layer-2 wide GEMM.
// Phase 1: h2tile[64][128] = elu([h1|s|ch] @ Bp1 + b3 + c*b1)  (K=192, in LDS)
// Phase 2: zuy[64 rows][192] = h2tile @ Bp2                    (K=128)
// Eliminates the h2 HBM round-trip (12.8 MB write + 12.8 MB read).
// LDS padded to [64][136] so phase-2 ds_read_b128 across rows spreads banks.
// ---------------------------------------------------------------------------
__global__ __launch_bounds__(256) void gemm_l1_fused(
    const u16* __restrict__ hb, const u16* __restrict__ sb,
    const u16* __restrict__ chb, const u16* __restrict__ Bp1,
    const u16* __restrict__ Bp2, const float* __restrict__ cvec,
    const float* __restrict__ bias1, const float* __restrict__ bias3,
    u16* __restrict__ zuy) {
    __shared__ u16 ht[64][136];
    const int tid = threadIdx.x;
    const int wv = tid >> 6;
    const int lane = tid & 63;
    const int l15 = lane & 15;
    const int q = lane >> 4;
    const int mhalf = wv & 1;
    const int nhalf = wv >> 1;
    const int row_base = blockIdx.x * 64 + mhalf * 32;
    const int r0 = min(row_base + l15, N_NODES - 1);
    const int r1 = min(row_base + 16 + l15, N_NODES - 1);
    const int qo = q * 8;

    // ---- phase 1: 32 rows x 64 cols per wave (nt tiles nt0..nt0+3), K=192
    {
        const int nt0 = nhalf * 4;
        f32x4 acc[2][4] = {};
#pragma unroll
        for (int chunk = 0; chunk < 6; chunk++) {
            const int region = chunk / 2;
            const int koff = (chunk - region * 2) * 32 + qo;
            const u16* A = (region == 0) ? hb : (region == 1) ? sb : chb;
            bf16x8 a0 = *(const bf16x8*)(A + (size_t)r0 * 64 + koff);
            bf16x8 a1 = *(const bf16x8*)(A + (size_t)r1 * 64 + koff);
#pragma unroll
            for (int ni = 0; ni < 4; ni++) {
                bf16x8 bf = *(const bf16x8*)(Bp1 + (((size_t)(chunk * 8 + nt0 + ni) * 64 + lane) << 3));
                acc[0][ni] = __builtin_amdgcn_mfma_f32_16x16x32_bf16(a0, bf, acc[0][ni], 0, 0, 0);
                acc[1][ni] = __builtin_amdgcn_mfma_f32_16x16x32_bf16(a1, bf, acc[1][ni], 0, 0, 0);
            }
        }
        // epilogue -> LDS (local coords; clamp cvec for rows >= N)
#pragma unroll
        for (int ni = 0; ni < 4; ni++) {
            const int col = (nt0 + ni) * 16 + l15;
            const float B3 = bias3[col];
            const float B1 = bias1[col];
#pragma unroll
            for (int mi = 0; mi < 2; mi++) {
#pragma unroll
                for (int reg = 0; reg < 4; reg++) {
                    const int lrow = mhalf * 32 + mi * 16 + q * 4 + reg;
                    const int grow = blockIdx.x * 64 + lrow;
                    const float cv = cvec[min(grow, N_NODES - 1)];
                    ht[lrow][col] = f2bf(elu_f(acc[mi][ni][reg] + B3 + cv * B1));
                }
            }
        }
    }
    __syncthreads();

    // ---- phase 2: 32 rows x 96 cols per wave (nt tiles nt2..nt2+5), K=128
    {
        const int nt2 = nhalf * 6;
        f32x4 acc[2][6] = {};
#pragma unroll
        for (int chunk = 0; chunk < 4; chunk++) {
            const int koff = chunk * 32 + qo;
            bf16x8 a0 = *(const bf16x8*)(&ht[mhalf * 32 + l15][koff]);
            bf16x8 a1 = *(const bf16x8*)(&ht[mhalf * 32 + 16 + l15][koff]);
#pragma unroll
            for (int ni = 0; ni < 6; ni++) {
                bf16x8 bf = *(const bf16x8*)(Bp2 + (((size_t)(chunk * 12 + nt2 + ni) * 64 + lane) << 3));
                acc[0][ni] = __builtin_amdgcn_mfma_f32_16x16x32_bf16(a0, bf, acc[0][ni], 0, 0, 0);
                acc[1][ni] = __builtin_amdgcn_mfma_f32_16x16x32_bf16(a1, bf, acc[1][ni], 0, 0, 0);
            }
        }
#pragma unroll
        for (int ni = 0; ni < 6; ni++) {
            const int col = (nt2 + ni) * 16 + l15;
#pragma unroll
            for (int mi = 0; mi < 2; mi++) {
#pragma unroll
                for (int reg = 0; reg < 4; reg++) {
                    const int row = row_base + mi * 16 + q * 4 + reg;
                    if (row < N_NODES)
                        zuy[(size_t)row * 192 + col] = f2bf(acc[mi][ni][reg]);
                }
            }
        }
    }
}

// ---------------------------------------------------------------------------
// Layer-2 gather + fused epilogue. zuy rows: [z(64) | u(64) | y(64)].
// h3[i] = elu( z_i + c_i*u_i + sum_e w_e * y[src_e] + b3 + c_i*b1 )
// ---------------------------------------------------------------------------
__global__ __launch_bounds__(256) void gather2_kernel(
    const u16* __restrict__ zuy, const int* __restrict__ rowptr,
    const int2* __restrict__ csr, const float* __restrict__ c,
    const float* __restrict__ bias1, const float* __restrict__ bias3,
    u16* __restrict__ h3) {
    constexpr int CG = 16, EG = 4;
    const int gid = blockIdx.x * 256 + threadIdx.x;
    const int node = gid >> 6;
    if (node >= N_NODES) return;
    const int lane = threadIdx.x & 63;
    const int cg = lane & (CG - 1);
    const int eg = lane >> 4;
    const int beg = rowptr[node];
    const int end = rowptr[node + 1];

    float a0 = 0.f, a1 = 0.f, a2 = 0.f, a3 = 0.f;
    float b0 = 0.f, b1 = 0.f, b2 = 0.f, b3 = 0.f;

    int p = beg + eg;
    for (; p + EG < end; p += 2 * EG) {
        int2 e0 = csr[p];
        int2 e1 = csr[p + EG];
        float w0 = __int_as_float(e0.y);
        float w1 = __int_as_float(e1.y);
        uint2 v0 = ((const uint2*)(zuy + (size_t)e0.x * 192 + 128))[cg];
        uint2 v1 = ((const uint2*)(zuy + (size_t)e1.x * 192 + 128))[cg];
        float f0, f1, f2, f3, g0, g1, g2, g3;
        bfpair(v0.x, f0, f1); bfpair(v0.y, f2, f3);
        bfpair(v1.x, g0, g1); bfpair(v1.y, g2, g3);
        a0 += w0 * f0; a1 += w0 * f1; a2 += w0 * f2; a3 += w0 * f3;
        b0 += w1 * g0; b1 += w1 * g1; b2 += w1 * g2; b3 += w1 * g3;
    }
    if (p < end) {
        int2 e0 = csr[p];
        float w0 = __int_as_float(e0.y);
        uint2 v0 = ((const uint2*)(zuy + (size_t)e0.x * 192 + 128))[cg];
        float f0, f1, f2, f3;
        bfpair(v0.x, f0, f1); bfpair(v0.y, f2, f3);
        a0 += w0 * f0; a1 += w0 * f1; a2 += w0 * f2; a3 += w0 * f3;
    }
    a0 += b0; a1 += b1; a2 += b2; a3 += b3;

#pragma unroll
    for (int off = 32; off >= CG; off >>= 1) {
        a0 += __shfl_xor(a0, off);
        a1 += __shfl_xor(a1, off);
        a2 += __shfl_xor(a2, off);
        a3 += __shfl_xor(a3, off);
    }

    if (lane < CG) {
        const float cn = c[node];
        const u16* zr = zuy + (size_t)node * 192;
        uint2 zv = ((const uint2*)zr)[cg];
        uint2 uv = ((const uint2*)(zr + 64))[cg];
        float z0, z1, z2, z3, u0, u1, u2, u3;
        bfpair(zv.x, z0, z1); bfpair(zv.y, z2, z3);
        bfpair(uv.x, u0, u1); bfpair(uv.y, u2, u3);
        const float4 b3v = *(const float4*)(bias3 + cg * 4);
        const float4 b1v = *(const float4*)(bias1 + cg * 4);
        float o0 = elu_f(z0 + cn * u0 + a0 + b3v.x + cn * b1v.x);
        float o1 = elu_f(z1 + cn * u1 + a1 + b3v.y + cn * b1v.y);
        float o2 = elu_f(z2 + cn * u2 + a2 + b3v.z + cn * b1v.z);
        float o3 = elu_f(z3 + cn * u3 + a3 + b3v.w + cn * b1v.w);
        uint2 o;
        o.x = packbf(o0, o1);
        o.y = packbf(o2, o3);
        ((uint2*)h3)[(size_t)node * CG + cg] = o;
    }
}

// ---------------------------------------------------------------------------
// out[g, :] = max over nodes of graph g of h[:, :64] (bf16 in, fp32 out)
// ---------------------------------------------------------------------------
__global__ void pool_kernel(const u16* __restrict__ h,
                            const int* __restrict__ batch,
                            float* __restrict__ out) {
    const int g = blockIdx.x;
    const int tid = threadIdx.x;
    int lo = 0, hi = N_NODES;
    while (lo < hi) { int mid = (lo + hi) >> 1; if (batch[mid] < g) lo = mid + 1; else hi = mid; }
    const int beg = lo;
    lo = beg; hi = N_NODES;
    while (lo < hi) { int mid = (lo + hi) >> 1; if (batch[mid] < g + 1) lo = mid + 1; else hi = mid; }
    const int end = lo;

    __shared__ float red[256];
    const int col = tid & 63;
    const int rg = tid >> 6;
    float m = -3.0e38f;
    for (int r = beg + rg; r < end; r += 4) m = fmaxf(m, bf2f(h[(size_t)r * 64 + col]));
    red[tid] = m;
    __syncthreads();
    if (tid < 64) {
        m = fmaxf(fmaxf(red[tid], red[tid + 64]), fmaxf(red[tid + 128], red[tid + 192]));
        out[g * 64 + tid] = m;
    }
}

extern "C" void kernel_launch(void* const* d_in, const int* in_sizes, int n_in,
                              void* d_out, int out_size, void* d_ws, size_t ws_size,
                              hipStream_t stream) {
    const float* x = (const float*)d_in[0];
    const int* ei = (const int*)d_in[1];
    const float* ea = (const float*)d_in[2];
    const int* batch = (const int*)d_in[3];
    const float* wfc = (const float*)d_in[4];
    const float* bfc = (const float*)d_in[5];
    const float* w1_0 = (const float*)d_in[6];
    const float* b1_0 = (const float*)d_in[7];
    const float* w2_0 = (const float*)d_in[8];
    const float* w3_0 = (const float*)d_in[9];
    const float* b3_0 = (const float*)d_in[10];
    const float* w1_1 = (const float*)d_in[11];
    const float* b1_1 = (const float*)d_in[12];
    const float* w2_1 = (const float*)d_in[13];
    const float* w3_1 = (const float*)d_in[14];
    const float* b3_1 = (const float*)d_in[15];
    const float* w1_2 = (const float*)d_in[16];
    const float* b1_2 = (const float*)d_in[17];
    const float* w2_2 = (const float*)d_in[18];
    const float* w3_2 = (const float*)d_in[19];
    const float* b3_2 = (const float*)d_in[20];
    float* out = (float*)d_out;

    char* ws = (char*)d_ws;
    float* ew      = (float*)(ws);                 // E f32      3.2 MB
    float* c       = (float*)(ws + 3200000);       // N f32
    int*   rowptr  = (int*)  (ws + 3800000);       // N+1 int
    int2*  csr     = (int2*) (ws + 4000128);       // E int2     6.4 MB
    u16*   xb      = (u16*)  (ws + 10400128);      // N*64 bf16  6.4 MB
    u16*   sb      = (u16*)  (ws + 16800128);      // N*128 bf16 12.8 MB
    u16*   chb     = (u16*)  (ws + 29600128);      // N*128 bf16 12.8 MB
    u16*   h1      = (u16*)  (ws + 42400128);      // N*64 bf16  6.4 MB
    u16*   zuy     = (u16*)  (ws + 48800128);      // N*192 bf16 19.2 MB (dedicated)
    u16*   bp0     = (u16*)  (ws + 68000128);      // 24 KB packed weights L0
    u16*   bp1     = (u16*)  (ws + 68024704);      // 48 KB L1
    u16*   bp2     = (u16*)  (ws + 68073856);      // 48 KB L2 wide
    int* blk_sums  = (int*)  (ws + 68123008);
    int* blk_offs  = (int*)  (ws + 68123520);
    // aliases into regions dead at time of use:
    u16* dst16   = chb;                        // 1.6 MB, dead before gather0
    u32* degpack = (u32*)(ws + 31600128);      // 100 KB (chb+2MB), dead before gather0
    u32* partial = (u32*)sb;                   // 12.8 MB, dead before gather0
    u32* prefpack = (u32*)zuy;                 // 12.8 MB, dead before gemm_l1_fused writes zuy
    u16* h3 = xb;                              // N*64 bf16 (xb dead after layer-0 gemm)

    conv_x_kernel<<<3125, 256, 0, stream>>>(x, xb);
    ew_kernel<<<(N_EDGES + 255) / 256, 256, 0, stream>>>(ea, wfc, bfc, ei, ew, dst16);
    pack_w_kernel<<<30, 256, 0, stream>>>(w3_0, w1_0, w2_0, w3_1, w1_1, w2_1,
                                          w3_2, w1_2, w2_2, bp0, bp1, bp2);
    deg_hist_kernel<<<HCHUNKS * 2, 256, 0, stream>>>(dst16, partial);
    scan_chunks_kernel<<<98, 256, 0, stream>>>(partial, prefpack, degpack);
    scan1_kernel<<<SCAN_NB, 256, 0, stream>>>(degpack, rowptr, blk_sums);
    scan2_kernel<<<1, 128, 0, stream>>>(blk_sums, blk_offs, rowptr);
    scan3_kernel<<<(N_NODES + 255) / 256, 256, 0, stream>>>(rowptr, blk_offs);
    place_kernel<<<HCHUNKS * NPASS, 256, 0, stream>>>(ei, ew, dst16, rowptr, prefpack, csr);

    const int RB = (N_NODES + 63) / 64;           // 782 row-blocks
    const int GBLK = (N_NODES * 64 + 255) / 256;  // one wave per node

    // layer 0: 64 -> 64
    gather_kernel<64, true><<<GBLK, 256, 0, stream>>>(xb, rowptr, csr, sb, chb, c);
    gemm_mfma<64, 64><<<dim3(RB, 1), 256, 0, stream>>>(xb, sb, chb, bp0, c, b1_0, b3_0, h1);

    // layer 1 + layer-2 wide GEMM fused: h2 never touches HBM
    gather_kernel<64, false><<<GBLK, 256, 0, stream>>>(h1, rowptr, csr, sb, chb, c);
    gemm_l1_fused<<<RB, 256, 0, stream>>>(h1, sb, chb, bp1, bp2, c, b1_1, b3_1, zuy);

    // layer 2 gather in output space + fused epilogue
    gather2_kernel<<<GBLK, 256, 0, stream>>>(zuy, rowptr, csr, c, b1_2, b3_2, h3);

    // global max pool
    pool_kernel<<<NUM_GRAPHS_, 256, 0, stream>>>(h3, batch, out);
}

// Round 6
// 329.221 us; speedup vs baseline: 1.6812x; 1.0250x over previous
//
#include <hip/hip_runtime.h>
#include <math.h>

#define N_NODES 50000
#define N_EDGES 800000
#define NUM_GRAPHS_ 128
#define SCAN_NB 98   // ceil(50000/512)
#define NPASS 8
#define NODES_PER_PASS 6250  // 50000/8
#define HCHUNKS 128
#define EDGES_PER_CHUNK 6250 // 800000/128
#define HWORDS 12500         // 25000 nodes per half, 2 per word
#define TS_BPH 196           // transpose-scan blocks per half: ceil(12500/64)

typedef unsigned short u16;
typedef unsigned int u32;
typedef __attribute__((ext_vector_type(8))) short bf16x8;   // 8 bf16 (4 VGPRs)
typedef __attribute__((ext_vector_type(4))) float f32x4;    // 4 fp32

__device__ __forceinline__ float elu_f(float v) {
    return v > 0.f ? v : (__expf(v) - 1.f);
}
__device__ __forceinline__ u16 f2bf(float f) {  // RNE
    u32 u = __float_as_uint(f);
    u += 0x7FFFu + ((u >> 16) & 1u);
    return (u16)(u >> 16);
}
__device__ __forceinline__ float bf2f(u16 h) {
    return __uint_as_float(((u32)h) << 16);
}
__device__ __forceinline__ void bfpair(u32 v, float& lo, float& hi) {
    lo = __uint_as_float(v << 16);
    hi = __uint_as_float(v & 0xFFFF0000u);
}
__device__ __forceinline__ u32 packbf(float lo, float hi) {
    return (u32)f2bf(lo) | ((u32)f2bf(hi) << 16);
}

// ---------------------------------------------------------------------------
// Fused prep: blocks [0,3125) edge weights + dst16; [3125,6250) x->bf16;
// [6250,6280) weight packing. Three independent start-of-chain kernels in one
// launch (saves 2 launch gaps on the serial dependency chain).
// ---------------------------------------------------------------------------
__global__ void prep_kernel(const float* __restrict__ edge_attr,
                            const float* __restrict__ w_fc1,
                            const float* __restrict__ b_fc1,
                            const int* __restrict__ edge_index,
                            float* __restrict__ ew,
                            u16* __restrict__ dst16,
                            const float* __restrict__ x, u16* __restrict__ xb,
                            const float* __restrict__ w3_0, const float* __restrict__ w1_0, const float* __restrict__ w2_0,
                            const float* __restrict__ w3_1, const float* __restrict__ w1_1, const float* __restrict__ w2_1,
                            const float* __restrict__ w3_2, const float* __restrict__ w1_2, const float* __restrict__ w2_2,
                            u16* __restrict__ bp0, u16* __restrict__ bp1, u16* __restrict__ bp2) {
    const int b = blockIdx.x;
    if (b < 3125) {
        // --- ew: edge weight + dst16
        const int e = b * 256 + threadIdx.x;
        const float4* ea = (const float4*)(edge_attr + (size_t)e * 16);
        const float4* wf = (const float4*)w_fc1;
        float acc = b_fc1[0];
#pragma unroll
        for (int i = 0; i < 4; i++) {
            float4 a = ea[i], w = wf[i];
            acc += a.x * w.x + a.y * w.y + a.z * w.z + a.w * w.w;
        }
        ew[e] = acc;
        dst16[e] = (u16)edge_index[N_EDGES + e];
    } else if (b < 6250) {
        // --- conv_x: fp32 -> bf16
        const int g = (b - 3125) * 256 + threadIdx.x;
        float4 v = ((const float4*)x)[g];
        uint2 o;
        o.x = packbf(v.x, v.y);
        o.y = packbf(v.z, v.w);
        ((uint2*)xb)[g] = o;
    } else {
        // --- pack_w
        const int t = (b - 6250) * 256 + threadIdx.x;
        u16 buf[8];
        if (t < 4608) {
            int DOUT, lid;
            const float *w3, *w1, *w2;
            u16* bp;
            if (t < 1536) { DOUT = 64;  lid = t;        w3 = w3_0; w1 = w1_0; w2 = w2_0; bp = bp0; }
            else          { DOUT = 128; lid = t - 1536; w3 = w3_1; w1 = w1_1; w2 = w2_1; bp = bp1; }
            const int NT = DOUT / 16;
            const int lane = lid & 63;
            const int fragid = lid >> 6;
            const int chunk = fragid / NT;
            const int ntile = fragid % NT;
            const int n = ntile * 16 + (lane & 15);
            const int kbase = chunk * 32 + (lane >> 4) * 8;
#pragma unroll
            for (int j = 0; j < 8; j++) {
                int k = kbase + j;
                int region = k / 64;
                int kk = k - region * 64;
                float v = (region == 0) ? w3[kk * DOUT + n]
                        : (region == 1) ? w1[kk * DOUT + n]
                                        : -w2[kk * DOUT + n];
                buf[j] = f2bf(v);
            }
            *(bf16x8*)(bp + ((size_t)lid << 3)) = *(bf16x8*)buf;
        } else if (t < 7680) {
            const int lid = t - 4608;          // 0..3071
            const int NT = 12;
            const int lane = lid & 63;
            const int fragid = lid >> 6;       // 0..47
            const int chunk = fragid / NT;     // 0..3
            const int ntile = fragid % NT;     // 0..11
            const int n = ntile * 16 + (lane & 15);   // 0..191
            const int kbase = chunk * 32 + (lane >> 4) * 8;  // 0..127
#pragma unroll
            for (int j = 0; j < 8; j++) {
                int k = kbase + j;
                float v = (n < 64)  ? w3_2[k * 64 + n]
                        : (n < 128) ? -w2_2[k * 64 + (n - 64)]
                                    : w1_2[k * 64 + (n - 128)];
                buf[j] = f2bf(v);
            }
            *(bf16x8*)(bp2 + ((size_t)lid << 3)) = *(bf16x8*)buf;
        }
    }
}

// ---------------------------------------------------------------------------
// Degree histogram per (chunk, half): LDS atomics only, dense write.
// ---------------------------------------------------------------------------
__global__ __launch_bounds__(256) void deg_hist_kernel(const u16* __restrict__ dst16,
                                                       u32* __restrict__ partial) {
    __shared__ u32 bins[HWORDS];
    const int c = blockIdx.x >> 1;
    const int p = blockIdx.x & 1;
    const int t = threadIdx.x;
    for (int i = t; i < HWORDS; i += 256) bins[i] = 0;
    __syncthreads();
    const int base = c * EDGES_PER_CHUNK;
    const int nlo = p * 25000;
    for (int i = t; i < EDGES_PER_CHUNK; i += 256) {
        const int b = (int)dst16[base + i] - nlo;
        if ((unsigned)b < 25000u)
            atomicAdd(&bins[b >> 1], 1u << ((b & 1) * 16));
    }
    __syncthreads();
    u32* outp = partial + (size_t)blockIdx.x * HWORDS;
    for (int i = t; i < HWORDS; i += 256) outp[i] = bins[i];
}

// ---------------------------------------------------------------------------
// Exclusive scan along the chunk axis, REGISTER-PARALLEL:
// thread (quarter cq, lane wl) privately owns chunks [cq*32, cq*32+32) of
// node-pair wh0+wl in 32 registers (statically unrolled), single LDS
// exchange for quarter prefixes. 32 independent coalesced loads/thread
// replaces the old 128-iteration serial dependent chain (latency-bound,
// ~1.5 waves/CU); now 1568 waves, BW-bound.
// ---------------------------------------------------------------------------
__global__ __launch_bounds__(256) void scan_chunks_kernel(const u32* __restrict__ partial,
                                                          u32* __restrict__ prefpack,
                                                          u32* __restrict__ degpack) {
    __shared__ u32 qsums[4][64];
    const int t = threadIdx.x;
    const int p = (blockIdx.x >= TS_BPH) ? 1 : 0;
    const int wh0 = (blockIdx.x - p * TS_BPH) << 6;
    const int wl = t & 63;
    const int cq = t >> 6;           // quarter: chunks [cq*32, cq*32+32)
    const int wh = wh0 + wl;
    const bool ok = wh < HWORDS;

    u32 vals[32];
#pragma unroll
    for (int i = 0; i < 32; i++) {
        const int c = cq * 32 + i;
        vals[i] = ok ? partial[(size_t)((c << 1) + p) * HWORDS + wh] : 0u;
    }
    u32 s = 0;
#pragma unroll
    for (int i = 0; i < 32; i++) s += vals[i];   // packed u16-pair add (no carry: deg << 65536)
    qsums[cq][wl] = s;
    __syncthreads();
    u32 run = 0;
#pragma unroll
    for (int j = 0; j < 4; j++)
        if (j < cq) run += qsums[j][wl];

    if (ok) {
        const int g = p * HWORDS + wh;
#pragma unroll
        for (int i = 0; i < 32; i++) {
            const int c = cq * 32 + i;
            prefpack[(size_t)c * 25000 + g] = run;
            run += vals[i];
        }
        if (cq == 3) degpack[g] = run;
    }
}

// ---------------------------------------------------------------------------
// Hierarchical exclusive scan of degpack -> rowptr[N+1]
// ---------------------------------------------------------------------------
__global__ __launch_bounds__(256) void scan1_kernel(const u32* __restrict__ degpack,
                                                    int* __restrict__ rowptr,
                                                    int* __restrict__ blk_sums) {
    __shared__ int sh[256];
    const int t = threadIdx.x;
    const int base = blockIdx.x * 512;
    const int i0 = base + 2 * t, i1 = i0 + 1;
    int d0 = 0, d1 = 0;
    if (i0 < N_NODES) {
        u32 v = degpack[i0 >> 1];
        d0 = (int)(v & 0xFFFFu);
        d1 = (int)(v >> 16);
    }
    const int pair = d0 + d1;
    int v = pair;
    sh[t] = v;
    __syncthreads();
#pragma unroll
    for (int off = 1; off < 256; off <<= 1) {
        int add = (t >= off) ? sh[t - off] : 0;
        __syncthreads();
        v += add;
        sh[t] = v;
        __syncthreads();
    }
    const int excl = v - pair;
    if (i0 < N_NODES) rowptr[i0] = excl;
    if (i1 < N_NODES) rowptr[i1] = excl + d0;
    if (t == 255) blk_sums[blockIdx.x] = v;
}

__global__ __launch_bounds__(128) void scan2_kernel(const int* __restrict__ blk_sums,
                                                    int* __restrict__ blk_offs,
                                                    int* __restrict__ rowptr) {
    __shared__ int sh[128];
    const int t = threadIdx.x;
    const int orig = (t < SCAN_NB) ? blk_sums[t] : 0;
    int v = orig;
    sh[t] = v;
    __syncthreads();
#pragma unroll
    for (int off = 1; off < 128; off <<= 1) {
        int add = (t >= off) ? sh[t - off] : 0;
        __syncthreads();
        v += add;
        sh[t] = v;
        __syncthreads();
    }
    if (t < SCAN_NB) blk_offs[t] = v - orig;
    if (t == 127) rowptr[N_NODES] = v;
}

__global__ void scan3_kernel(int* __restrict__ rowptr,
                             const int* __restrict__ blk_offs) {
    int i = blockIdx.x * blockDim.x + threadIdx.x;
    if (i >= N_NODES) return;
    rowptr[i] += blk_offs[i >> 9];
}

// ---------------------------------------------------------------------------
// CSR placement, NO global atomics (counting sort).
// Block (chunk c, pass p): slot = rowptr[d] + prefpack[c][d] + LDS local rank.
// pass = blockIdx&7 keeps each pass's 800KB csr region on one XCD.
// ---------------------------------------------------------------------------
__global__ __launch_bounds__(256) void place_kernel(const int* __restrict__ edge_index,
                                                    const float* __restrict__ ew,
                                                    const u16* __restrict__ dst16,
                                                    const int* __restrict__ rowptr,
                                                    const u32* __restrict__ prefpack,
                                                    int2* __restrict__ csr) {
    __shared__ int lcur[NODES_PER_PASS];
    const int pass = blockIdx.x & (NPASS - 1);
    const int c = blockIdx.x >> 3;
    const int lo = pass * NODES_PER_PASS;
    const int t = threadIdx.x;
    for (int i = t; i < NODES_PER_PASS; i += 256) lcur[i] = 0;
    __syncthreads();
    const int base = c * EDGES_PER_CHUNK;
    for (int i = t; i < EDGES_PER_CHUNK; i += 256) {
        const int e = base + i;
        const int d = (int)dst16[e];
        const int dl = d - lo;
        if ((unsigned)dl < (unsigned)NODES_PER_PASS) {
            u32 pw = prefpack[(size_t)c * 25000 + (d >> 1)];
            int pref = (int)((pw >> ((d & 1) * 16)) & 0xFFFFu);
            int lpos = atomicAdd(&lcur[dl], 1);
            int2 ent;
            ent.x = edge_index[e];
            ent.y = __float_as_int(ew[e]);
            csr[rowptr[d] + pref + lpos] = ent;
        }
    }
}

// ---------------------------------------------------------------------------
// Gather aggregation (bf16, fp32 accumulate), one WAVE per node. Layers 0/1.
// Writes s and ch = c*h; layer 0 also emits c.
// ---------------------------------------------------------------------------
template <int DIN, bool WRITE_C>
__global__ __launch_bounds__(256) void gather_kernel(
    const u16* __restrict__ xb, const int* __restrict__ rowptr,
    const int2* __restrict__ csr, u16* __restrict__ sb,
    u16* __restrict__ chb, float* __restrict__ c) {
    constexpr int CG = DIN / 4;
    constexpr int EG = 64 / CG;
    const int gid = blockIdx.x * 256 + threadIdx.x;
    const int node = gid >> 6;
    if (node >= N_NODES) return;
    const int lane = threadIdx.x & 63;
    const int cg = lane & (CG - 1);
    const int eg = lane / CG;
    const int beg = rowptr[node];
    const int end = rowptr[node + 1];
    const uint2* x2 = (const uint2*)xb;

    float a0 = 0.f, a1 = 0.f, a2 = 0.f, a3 = 0.f;
    float b0 = 0.f, b1 = 0.f, b2 = 0.f, b3 = 0.f;
    float wsum = 0.f;

    int p = beg + eg;
    for (; p + EG < end; p += 2 * EG) {
        int2 e0 = csr[p];
        int2 e1 = csr[p + EG];
        float w0 = __int_as_float(e0.y);
        float w1 = __int_as_float(e1.y);
        uint2 v0 = x2[(size_t)e0.x * CG + cg];
        uint2 v1 = x2[(size_t)e1.x * CG + cg];
        float f0, f1, f2, f3, g0, g1, g2, g3;
        bfpair(v0.x, f0, f1); bfpair(v0.y, f2, f3);
        bfpair(v1.x, g0, g1); bfpair(v1.y, g2, g3);
        a0 += w0 * f0; a1 += w0 * f1; a2 += w0 * f2; a3 += w0 * f3;
        b0 += w1 * g0; b1 += w1 * g1; b2 += w1 * g2; b3 += w1 * g3;
        wsum += w0 + w1;
    }
    if (p < end) {
        int2 e0 = csr[p];
        float w0 = __int_as_float(e0.y);
        uint2 v0 = x2[(size_t)e0.x * CG + cg];
        float f0, f1, f2, f3;
        bfpair(v0.x, f0, f1); bfpair(v0.y, f2, f3);
        a0 += w0 * f0; a1 += w0 * f1; a2 += w0 * f2; a3 += w0 * f3;
        wsum += w0;
    }
    a0 += b0; a1 += b1; a2 += b2; a3 += b3;

#pragma unroll
    for (int off = 32; off >= CG; off >>= 1) {
        a0 += __shfl_xor(a0, off);
        a1 += __shfl_xor(a1, off);
        a2 += __shfl_xor(a2, off);
        a3 += __shfl_xor(a3, off);
        wsum += __shfl_xor(wsum, off);
    }

    if (lane < CG) {
        uint2 so;
        so.x = packbf(a0, a1);
        so.y = packbf(a2, a3);
        ((uint2*)sb)[(size_t)node * CG + cg] = so;
        const float cn = WRITE_C ? wsum : c[node];
        uint2 hv = x2[(size_t)node * CG + cg];
        float h0, h1, h2, h3;
        bfpair(hv.x, h0, h1); bfpair(hv.y, h2, h3);
        uint2 co;
        co.x = packbf(cn * h0, cn * h1);
        co.y = packbf(cn * h2, cn * h3);
        ((uint2*)chb)[(size_t)node * CG + cg] = co;
    }
    if (WRITE_C && lane == 0) c[node] = wsum;
}

// ---------------------------------------------------------------------------
// MFMA GEMM (layer 0): out = elu( [h|s|ch] @ Bp + b3 + c*b1 )
// ---------------------------------------------------------------------------
template <int DIN, int DOUT>
__global__ __launch_bounds__(256) void gemm_mfma(
    const u16* __restrict__ hb, const u16* __restrict__ sb,
    const u16* __restrict__ chb, const u16* __restrict__ Bp,
    const float* __restrict__ cvec, const float* __restrict__ bias1,
    const float* __restrict__ bias3, u16* __restrict__ outp) {
    constexpr int CH = DIN / 32;
    constexpr int CHUNKS = 3 * CH;
    constexpr int NT = DOUT / 16;
    const int tid = threadIdx.x;
    const int wv = tid >> 6;
    const int lane = tid & 63;
    const int l15 = lane & 15;
    const int q = lane >> 4;
    const int mhalf = wv & 1;
    const int nhalf = wv >> 1;
    const int row_base = blockIdx.x * 64 + mhalf * 32;
    const int nt0 = blockIdx.y * 4 + nhalf * 2;

    const int r0 = min(row_base + l15, N_NODES - 1);
    const int r1 = min(row_base + 16 + l15, N_NODES - 1);
    const int qo = q * 8;

    f32x4 acc00 = {0.f, 0.f, 0.f, 0.f};
    f32x4 acc01 = {0.f, 0.f, 0.f, 0.f};
    f32x4 acc10 = {0.f, 0.f, 0.f, 0.f};
    f32x4 acc11 = {0.f, 0.f, 0.f, 0.f};

#pragma unroll
    for (int chunk = 0; chunk < CHUNKS; chunk++) {
        const int region = chunk / CH;
        const int koff = (chunk - region * CH) * 32 + qo;
        const u16* A = (region == 0) ? hb : (region == 1) ? sb : chb;
        bf16x8 a0 = *(const bf16x8*)(A + (size_t)r0 * DIN + koff);
        bf16x8 a1 = *(const bf16x8*)(A + (size_t)r1 * DIN + koff);
        const u16* bp = Bp + (((size_t)(chunk * NT + nt0) * 64 + lane) << 3);
        bf16x8 bf0 = *(const bf16x8*)bp;
        bf16x8 bf1 = *(const bf16x8*)(bp + 64 * 8);
        acc00 = __builtin_amdgcn_mfma_f32_16x16x32_bf16(a0, bf0, acc00, 0, 0, 0);
        acc01 = __builtin_amdgcn_mfma_f32_16x16x32_bf16(a0, bf1, acc01, 0, 0, 0);
        acc10 = __builtin_amdgcn_mfma_f32_16x16x32_bf16(a1, bf0, acc10, 0, 0, 0);
        acc11 = __builtin_amdgcn_mfma_f32_16x16x32_bf16(a1, bf1, acc11, 0, 0, 0);
    }

#pragma unroll
    for (int ni = 0; ni < 2; ni++) {
        const int col = (nt0 + ni) * 16 + l15;
        const float B3 = bias3[col];
        const float B1 = bias1[col];
        const f32x4 am0 = ni ? acc01 : acc00;
        const f32x4 am1 = ni ? acc11 : acc10;
#pragma unroll
        for (int mi = 0; mi < 2; mi++) {
            const f32x4 av = mi ? am1 : am0;
#pragma unroll
            for (int reg = 0; reg < 4; reg++) {
                const int row = row_base + mi * 16 + q * 4 + reg;
                if (row < N_NODES) {
                    const float cv = cvec[row];
                    const float val = av[reg] + B3 + cv * B1;
                    outp[(size_t)row * DOUT + col] = f2bf(elu_f(val));
                }
            }
        }
    }
}

// ---------------------------------------------------------------------------
// FUSED layer-1 GEMM + layer-2 wide GEMM.
// Phase 1: h2tile[64][128] = elu([h1|s|ch] @ Bp1 + b3 + c*b1)  (K=192, in LDS)
// Phase 2: zuy[64 rows][192] = h2tile @ Bp2                    (K=128)
// Eliminates the h2 HBM round-trip (12.8 MB write + 12.8 MB read).
// LDS padded to [64][136] so phase-2 ds_read_b128 across rows spreads banks.
// ---------------------------------------------------------------------------
__global__ __launch_bounds__(256) void gemm_l1_fused(
    const u16* __restrict__ hb, const u16* __restrict__ sb,
    const u16* __restrict__ chb, const u16* __restrict__ Bp1,
    const u16* __restrict__ Bp2, const float* __restrict__ cvec,
    const float* __restrict__ bias1, const float* __restrict__ bias3,
    u16* __restrict__ zuy) {
    __shared__ u16 ht[64][136];
    const int tid = threadIdx.x;
    const int wv = tid >> 6;
    const int lane = tid & 63;
    const int l15 = lane & 15;
    const int q = lane >> 4;
    const int mhalf = wv & 1;
    const int nhalf = wv >> 1;
    const int row_base = blockIdx.x * 64 + mhalf * 32;
    const int r0 = min(row_base + l15, N_NODES - 1);
    const int r1 = min(row_base + 16 + l15, N_NODES - 1);
    const int qo = q * 8;

    // ---- phase 1: 32 rows x 64 cols per wave (nt tiles nt0..nt0+3), K=192
    {
        const int nt0 = nhalf * 4;
        f32x4 acc[2][4] = {};
#pragma unroll
        for (int chunk = 0; chunk < 6; chunk++) {
            const int region = chunk / 2;
            const int koff = (chunk - region * 2) * 32 + qo;
            const u16* A = (region == 0) ? hb : (region == 1) ? sb : chb;
            bf16x8 a0 = *(const bf16x8*)(A + (size_t)r0 * 64 + koff);
            bf16x8 a1 = *(const bf16x8*)(A + (size_t)r1 * 64 + koff);
#pragma unroll
            for (int ni = 0; ni < 4; ni++) {
                bf16x8 bf = *(const bf16x8*)(Bp1 + (((size_t)(chunk * 8 + nt0 + ni) * 64 + lane) << 3));
                acc[0][ni] = __builtin_amdgcn_mfma_f32_16x16x32_bf16(a0, bf, acc[0][ni], 0, 0, 0);
                acc[1][ni] = __builtin_amdgcn_mfma_f32_16x16x32_bf16(a1, bf, acc[1][ni], 0, 0, 0);
            }
        }
        // epilogue -> LDS (local coords; clamp cvec for rows >= N)
#pragma unroll
        for (int ni = 0; ni < 4; ni++) {
            const int col = (nt0 + ni) * 16 + l15;
            const float B3 = bias3[col];
            const float B1 = bias1[col];
#pragma unroll
            for (int mi = 0; mi < 2; mi++) {
#pragma unroll
                for (int reg = 0; reg < 4; reg++) {
                    const int lrow = mhalf * 32 + mi * 16 + q * 4 + reg;
                    const int grow = blockIdx.x * 64 + lrow;
                    const float cv = cvec[min(grow, N_NODES - 1)];
                    ht[lrow][col] = f2bf(elu_f(acc[mi][ni][reg] + B3 + cv * B1));
                }
            }
        }
    }
    __syncthreads();

    // ---- phase 2: 32 rows x 96 cols per wave (nt tiles nt2..nt2+5), K=128
    {
        const int nt2 = nhalf * 6;
        f32x4 acc[2][6] = {};
#pragma unroll
        for (int chunk = 0; chunk < 4; chunk++) {
            const int koff = chunk * 32 + qo;
            bf16x8 a0 = *(const bf16x8*)(&ht[mhalf * 32 + l15][koff]);
            bf16x8 a1 = *(const bf16x8*)(&ht[mhalf * 32 + 16 + l15][koff]);
#pragma unroll
            for (int ni = 0; ni < 6; ni++) {
                bf16x8 bf = *(const bf16x8*)(Bp2 + (((size_t)(chunk * 12 + nt2 + ni) * 64 + lane) << 3));
                acc[0][ni] = __builtin_amdgcn_mfma_f32_16x16x32_bf16(a0, bf, acc[0][ni], 0, 0, 0);
                acc[1][ni] = __builtin_amdgcn_mfma_f32_16x16x32_bf16(a1, bf, acc[1][ni], 0, 0, 0);
            }
        }
#pragma unroll
        for (int ni = 0; ni < 6; ni++) {
            const int col = (nt2 + ni) * 16 + l15;
#pragma unroll
            for (int mi = 0; mi < 2; mi++) {
#pragma unroll
                for (int reg = 0; reg < 4; reg++) {
                    const int row = row_base + mi * 16 + q * 4 + reg;
                    if (row < N_NODES)
                        zuy[(size_t)row * 192 + col] = f2bf(acc[mi][ni][reg]);
                }
            }
        }
    }
}

// ---------------------------------------------------------------------------
// Layer-2 gather + fused epilogue. zuy rows: [z(64) | u(64) | y(64)].
// h3[i] = elu( z_i + c_i*u_i + sum_e w_e * y[src_e] + b3 + c_i*b1 )
// ---------------------------------------------------------------------------
__global__ __launch_bounds__(256) void gather2_kernel(
    const u16* __restrict__ zuy, const int* __restrict__ rowptr,
    const int2* __restrict__ csr, const float* __restrict__ c,
    const float* __restrict__ bias1, const float* __restrict__ bias3,
    u16* __restrict__ h3) {
    constexpr int CG = 16, EG = 4;
    const int gid = blockIdx.x * 256 + threadIdx.x;
    const int node = gid >> 6;
    if (node >= N_NODES) return;
    const int lane = threadIdx.x & 63;
    const int cg = lane & (CG - 1);
    const int eg = lane >> 4;
    const int beg = rowptr[node];
    const int end = rowptr[node + 1];

    float a0 = 0.f, a1 = 0.f, a2 = 0.f, a3 = 0.f;
    float b0 = 0.f, b1 = 0.f, b2 = 0.f, b3 = 0.f;

    int p = beg + eg;
    for (; p + EG < end; p += 2 * EG) {
        int2 e0 = csr[p];
        int2 e1 = csr[p + EG];
        float w0 = __int_as_float(e0.y);
        float w1 = __int_as_float(e1.y);
        uint2 v0 = ((const uint2*)(zuy + (size_t)e0.x * 192 + 128))[cg];
        uint2 v1 = ((const uint2*)(zuy + (size_t)e1.x * 192 + 128))[cg];
        float f0, f1, f2, f3, g0, g1, g2, g3;
        bfpair(v0.x, f0, f1); bfpair(v0.y, f2, f3);
        bfpair(v1.x, g0, g1); bfpair(v1.y, g2, g3);
        a0 += w0 * f0; a1 += w0 * f1; a2 += w0 * f2; a3 += w0 * f3;
        b0 += w1 * g0; b1 += w1 * g1; b2 += w1 * g2; b3 += w1 * g3;
    }
    if (p < end) {
        int2 e0 = csr[p];
        float w0 = __int_as_float(e0.y);
        uint2 v0 = ((const uint2*)(zuy + (size_t)e0.x * 192 + 128))[cg];
        float f0, f1, f2, f3;
        bfpair(v0.x, f0, f1); bfpair(v0.y, f2, f3);
        a0 += w0 * f0; a1 += w0 * f1; a2 += w0 * f2; a3 += w0 * f3;
    }
    a0 += b0; a1 += b1; a2 += b2; a3 += b3;

#pragma unroll
    for (int off = 32; off >= CG; off >>= 1) {
        a0 += __shfl_xor(a0, off);
        a1 += __shfl_xor(a1, off);
        a2 += __shfl_xor(a2, off);
        a3 += __shfl_xor(a3, off);
    }

    if (lane < CG) {
        const float cn = c[node];
        const u16* zr = zuy + (size_t)node * 192;
        uint2 zv = ((const uint2*)zr)[cg];
        uint2 uv = ((const uint2*)(zr + 64))[cg];
        float z0, z1, z2, z3, u0, u1, u2, u3;
        bfpair(zv.x, z0, z1); bfpair(zv.y, z2, z3);
        bfpair(uv.x, u0, u1); bfpair(uv.y, u2, u3);
        const float4 b3v = *(const float4*)(bias3 + cg * 4);
        const float4 b1v = *(const float4*)(bias1 + cg * 4);
        float o0 = elu_f(z0 + cn * u0 + a0 + b3v.x + cn * b1v.x);
        float o1 = elu_f(z1 + cn * u1 + a1 + b3v.y + cn * b1v.y);
        float o2 = elu_f(z2 + cn * u2 + a2 + b3v.z + cn * b1v.z);
        float o3 = elu_f(z3 + cn * u3 + a3 + b3v.w + cn * b1v.w);
        uint2 o;
        o.x = packbf(o0, o1);
        o.y = packbf(o2, o3);
        ((uint2*)h3)[(size_t)node * CG + cg] = o;
    }
}

// ---------------------------------------------------------------------------
// out[g, :] = max over nodes of graph g of h[:, :64] (bf16 in, fp32 out)
// ---------------------------------------------------------------------------
__global__ void pool_kernel(const u16* __restrict__ h,
                            const int* __restrict__ batch,
                            float* __restrict__ out) {
    const int g = blockIdx.x;
    const int tid = threadIdx.x;
    int lo = 0, hi = N_NODES;
    while (lo < hi) { int mid = (lo + hi) >> 1; if (batch[mid] < g) lo = mid + 1; else hi = mid; }
    const int beg = lo;
    lo = beg; hi = N_NODES;
    while (lo < hi) { int mid = (lo + hi) >> 1; if (batch[mid] < g + 1) lo = mid + 1; else hi = mid; }
    const int end = lo;

    __shared__ float red[256];
    const int col = tid & 63;
    const int rg = tid >> 6;
    float m = -3.0e38f;
    for (int r = beg + rg; r < end; r += 4) m = fmaxf(m, bf2f(h[(size_t)r * 64 + col]));
    red[tid] = m;
    __syncthreads();
    if (tid < 64) {
        m = fmaxf(fmaxf(red[tid], red[tid + 64]), fmaxf(red[tid + 128], red[tid + 192]));
        out[g * 64 + tid] = m;
    }
}

extern "C" void kernel_launch(void* const* d_in, const int* in_sizes, int n_in,
                              void* d_out, int out_size, void* d_ws, size_t ws_size,
                              hipStream_t stream) {
    const float* x = (const float*)d_in[0];
    const int* ei = (const int*)d_in[1];
    const float* ea = (const float*)d_in[2];
    const int* batch = (const int*)d_in[3];
    const float* wfc = (const float*)d_in[4];
    const float* bfc = (const float*)d_in[5];
    const float* w1_0 = (const float*)d_in[6];
    const float* b1_0 = (const float*)d_in[7];
    const float* w2_0 = (const float*)d_in[8];
    const float* w3_0 = (const float*)d_in[9];
    const float* b3_0 = (const float*)d_in[10];
    const float* w1_1 = (const float*)d_in[11];
    const float* b1_1 = (const float*)d_in[12];
    const float* w2_1 = (const float*)d_in[13];
    const float* w3_1 = (const float*)d_in[14];
    const float* b3_1 = (const float*)d_in[15];
    const float* w1_2 = (const float*)d_in[16];
    const float* b1_2 = (const float*)d_in[17];
    const float* w2_2 = (const float*)d_in[18];
    const float* w3_2 = (const float*)d_in[19];
    const float* b3_2 = (const float*)d_in[20];
    float* out = (float*)d_out;

    char* ws = (char*)d_ws;
    float* ew      = (float*)(ws);                 // E f32      3.2 MB
    float* c       = (float*)(ws + 3200000);       // N f32
    int*   rowptr  = (int*)  (ws + 3800000);       // N+1 int
    int2*  csr     = (int2*) (ws + 4000128);       // E int2     6.4 MB
    u16*   xb      = (u16*)  (ws + 10400128);      // N*64 bf16  6.4 MB
    u16*   sb      = (u16*)  (ws + 16800128);      // N*128 bf16 12.8 MB
    u16*   chb     = (u16*)  (ws + 29600128);      // N*128 bf16 12.8 MB
    u16*   h1      = (u16*)  (ws + 42400128);      // N*64 bf16  6.4 MB
    u16*   zuy     = (u16*)  (ws + 48800128);      // N*192 bf16 19.2 MB (dedicated)
    u16*   bp0     = (u16*)  (ws + 68000128);      // 24 KB packed weights L0
    u16*   bp1     = (u16*)  (ws + 68024704);      // 48 KB L1
    u16*   bp2     = (u16*)  (ws + 68073856);      // 48 KB L2 wide
    int* blk_sums  = (int*)  (ws + 68123008);
    int* blk_offs  = (int*)  (ws + 68123520);
    // aliases into regions dead at time of use:
    u16* dst16   = chb;                        // 1.6 MB, dead before gather0
    u32* degpack = (u32*)(ws + 31600128);      // 100 KB (chb+2MB), dead before gather0
    u32* partial = (u32*)sb;                   // 12.8 MB, dead before gather0
    u32* prefpack = (u32*)zuy;                 // 12.8 MB, dead before gemm_l1_fused writes zuy
    u16* h3 = xb;                              // N*64 bf16 (xb dead after layer-0 gemm)

    // fused prep: ew + conv_x + pack_w in one launch
    prep_kernel<<<6280, 256, 0, stream>>>(ea, wfc, bfc, ei, ew, dst16, x, xb,
                                          w3_0, w1_0, w2_0, w3_1, w1_1, w2_1,
                                          w3_2, w1_2, w2_2, bp0, bp1, bp2);
    deg_hist_kernel<<<HCHUNKS * 2, 256, 0, stream>>>(dst16, partial);
    scan_chunks_kernel<<<TS_BPH * 2, 256, 0, stream>>>(partial, prefpack, degpack);
    scan1_kernel<<<SCAN_NB, 256, 0, stream>>>(degpack, rowptr, blk_sums);
    scan2_kernel<<<1, 128, 0, stream>>>(blk_sums, blk_offs, rowptr);
    scan3_kernel<<<(N_NODES + 255) / 256, 256, 0, stream>>>(rowptr, blk_offs);
    place_kernel<<<HCHUNKS * NPASS, 256, 0, stream>>>(ei, ew, dst16, rowptr, prefpack, csr);

    const int RB = (N_NODES + 63) / 64;           // 782 row-blocks
    const int GBLK = (N_NODES * 64 + 255) / 256;  // one wave per node

    // layer 0: 64 -> 64
    gather_kernel<64, true><<<GBLK, 256, 0, stream>>>(xb, rowptr, csr, sb, chb, c);
    gemm_mfma<64, 64><<<dim3(RB, 1), 256, 0, stream>>>(xb, sb, chb, bp0, c, b1_0, b3_0, h1);

    // layer 1 + layer-2 wide GEMM fused: h2 never touches HBM
    gather_kernel<64, false><<<GBLK, 256, 0, stream>>>(h1, rowptr, csr, sb, chb, c);
    gemm_l1_fused<<<RB, 256, 0, stream>>>(h1, sb, chb, bp1, bp2, c, b1_1, b3_1, zuy);

    // layer 2 gather in output space + fused epilogue
    gather2_kernel<<<GBLK, 256, 0, stream>>>(zuy, rowptr, csr, c, b1_2, b3_2, h3);

    // global max pool
    pool_kernel<<<NUM_GRAPHS_, 256, 0, stream>>>(h3, batch, out);
}

// Round 7
// 318.461 us; speedup vs baseline: 1.7380x; 1.0338x over previous
//
#include <hip/hip_runtime.h>
#include <math.h>

#define N_NODES 50000
#define N_EDGES 800000
#define NUM_GRAPHS_ 128
#define SCAN_NB 98   // ceil(50000/512)
#define NPASS 4
#define NODES_PER_PASS 12500 // 50000/4
#define HCHUNKS 128
#define EDGES_PER_CHUNK 6250 // 800000/128
#define HWORDS 12500         // 25000 nodes per half, 2 per word
#define TS_BPH 196           // transpose-scan blocks per half: ceil(12500/64)

typedef unsigned short u16;
typedef unsigned int u32;
typedef __attribute__((ext_vector_type(8))) short bf16x8;   // 8 bf16 (4 VGPRs)
typedef __attribute__((ext_vector_type(4))) float f32x4;    // 4 fp32

__device__ __forceinline__ float elu_f(float v) {
    return v > 0.f ? v : (__expf(v) - 1.f);
}
__device__ __forceinline__ u16 f2bf(float f) {  // RNE
    u32 u = __float_as_uint(f);
    u += 0x7FFFu + ((u >> 16) & 1u);
    return (u16)(u >> 16);
}
__device__ __forceinline__ float bf2f(u16 h) {
    return __uint_as_float(((u32)h) << 16);
}
__device__ __forceinline__ void bfpair(u32 v, float& lo, float& hi) {
    lo = __uint_as_float(v << 16);
    hi = __uint_as_float(v & 0xFFFF0000u);
}
__device__ __forceinline__ u32 packbf(float lo, float hi) {
    return (u32)f2bf(lo) | ((u32)f2bf(hi) << 16);
}

// ---------------------------------------------------------------------------
// Fused prep: blocks [0,3125) edge weights + dst16; [3125,6250) x->bf16;
// [6250,6280) weight packing.
// ---------------------------------------------------------------------------
__global__ void prep_kernel(const float* __restrict__ edge_attr,
                            const float* __restrict__ w_fc1,
                            const float* __restrict__ b_fc1,
                            const int* __restrict__ edge_index,
                            float* __restrict__ ew,
                            u16* __restrict__ dst16,
                            const float* __restrict__ x, u16* __restrict__ xb,
                            const float* __restrict__ w3_0, const float* __restrict__ w1_0, const float* __restrict__ w2_0,
                            const float* __restrict__ w3_1, const float* __restrict__ w1_1, const float* __restrict__ w2_1,
                            const float* __restrict__ w3_2, const float* __restrict__ w1_2, const float* __restrict__ w2_2,
                            u16* __restrict__ bp0, u16* __restrict__ bp1, u16* __restrict__ bp2) {
    const int b = blockIdx.x;
    if (b < 3125) {
        const int e = b * 256 + threadIdx.x;
        const float4* ea = (const float4*)(edge_attr + (size_t)e * 16);
        const float4* wf = (const float4*)w_fc1;
        float acc = b_fc1[0];
#pragma unroll
        for (int i = 0; i < 4; i++) {
            float4 a = ea[i], w = wf[i];
            acc += a.x * w.x + a.y * w.y + a.z * w.z + a.w * w.w;
        }
        ew[e] = acc;
        dst16[e] = (u16)edge_index[N_EDGES + e];
    } else if (b < 6250) {
        const int g = (b - 3125) * 256 + threadIdx.x;
        float4 v = ((const float4*)x)[g];
        uint2 o;
        o.x = packbf(v.x, v.y);
        o.y = packbf(v.z, v.w);
        ((uint2*)xb)[g] = o;
    } else {
        const int t = (b - 6250) * 256 + threadIdx.x;
        u16 buf[8];
        if (t < 4608) {
            int DOUT, lid;
            const float *w3, *w1, *w2;
            u16* bp;
            if (t < 1536) { DOUT = 64;  lid = t;        w3 = w3_0; w1 = w1_0; w2 = w2_0; bp = bp0; }
            else          { DOUT = 128; lid = t - 1536; w3 = w3_1; w1 = w1_1; w2 = w2_1; bp = bp1; }
            const int NT = DOUT / 16;
            const int lane = lid & 63;
            const int fragid = lid >> 6;
            const int chunk = fragid / NT;
            const int ntile = fragid % NT;
            const int n = ntile * 16 + (lane & 15);
            const int kbase = chunk * 32 + (lane >> 4) * 8;
#pragma unroll
            for (int j = 0; j < 8; j++) {
                int k = kbase + j;
                int region = k / 64;
                int kk = k - region * 64;
                float v = (region == 0) ? w3[kk * DOUT + n]
                        : (region == 1) ? w1[kk * DOUT + n]
                                        : -w2[kk * DOUT + n];
                buf[j] = f2bf(v);
            }
            *(bf16x8*)(bp + ((size_t)lid << 3)) = *(bf16x8*)buf;
        } else if (t < 7680) {
            const int lid = t - 4608;          // 0..3071
            const int NT = 12;
            const int lane = lid & 63;
            const int fragid = lid >> 6;       // 0..47
            const int chunk = fragid / NT;     // 0..3
            const int ntile = fragid % NT;     // 0..11
            const int n = ntile * 16 + (lane & 15);   // 0..191
            const int kbase = chunk * 32 + (lane >> 4) * 8;  // 0..127
#pragma unroll
            for (int j = 0; j < 8; j++) {
                int k = kbase + j;
                float v = (n < 64)  ? w3_2[k * 64 + n]
                        : (n < 128) ? -w2_2[k * 64 + (n - 64)]
                                    : w1_2[k * 64 + (n - 128)];
                buf[j] = f2bf(v);
            }
            *(bf16x8*)(bp2 + ((size_t)lid << 3)) = *(bf16x8*)buf;
        }
    }
}

// ---------------------------------------------------------------------------
// Degree histogram per (chunk, half): LDS atomics only, dense write.
// ---------------------------------------------------------------------------
__global__ __launch_bounds__(256) void deg_hist_kernel(const u16* __restrict__ dst16,
                                                       u32* __restrict__ partial) {
    __shared__ u32 bins[HWORDS];
    const int c = blockIdx.x >> 1;
    const int p = blockIdx.x & 1;
    const int t = threadIdx.x;
    for (int i = t; i < HWORDS; i += 256) bins[i] = 0;
    __syncthreads();
    const int base = c * EDGES_PER_CHUNK;
    const int nlo = p * 25000;
    for (int i = t; i < EDGES_PER_CHUNK; i += 256) {
        const int b = (int)dst16[base + i] - nlo;
        if ((unsigned)b < 25000u)
            atomicAdd(&bins[b >> 1], 1u << ((b & 1) * 16));
    }
    __syncthreads();
    u32* outp = partial + (size_t)blockIdx.x * HWORDS;
    for (int i = t; i < HWORDS; i += 256) outp[i] = bins[i];
}

// ---------------------------------------------------------------------------
// Exclusive scan along the chunk axis, register-parallel (32 chunks/thread).
// ---------------------------------------------------------------------------
__global__ __launch_bounds__(256) void scan_chunks_kernel(const u32* __restrict__ partial,
                                                          u32* __restrict__ prefpack,
                                                          u32* __restrict__ degpack) {
    __shared__ u32 qsums[4][64];
    const int t = threadIdx.x;
    const int p = (blockIdx.x >= TS_BPH) ? 1 : 0;
    const int wh0 = (blockIdx.x - p * TS_BPH) << 6;
    const int wl = t & 63;
    const int cq = t >> 6;           // quarter: chunks [cq*32, cq*32+32)
    const int wh = wh0 + wl;
    const bool ok = wh < HWORDS;

    u32 vals[32];
#pragma unroll
    for (int i = 0; i < 32; i++) {
        const int c = cq * 32 + i;
        vals[i] = ok ? partial[(size_t)((c << 1) + p) * HWORDS + wh] : 0u;
    }
    u32 s = 0;
#pragma unroll
    for (int i = 0; i < 32; i++) s += vals[i];
    qsums[cq][wl] = s;
    __syncthreads();
    u32 run = 0;
#pragma unroll
    for (int j = 0; j < 4; j++)
        if (j < cq) run += qsums[j][wl];

    if (ok) {
        const int g = p * HWORDS + wh;
#pragma unroll
        for (int i = 0; i < 32; i++) {
            const int c = cq * 32 + i;
            prefpack[(size_t)c * 25000 + g] = run;
            run += vals[i];
        }
        if (cq == 3) degpack[g] = run;
    }
}

// ---------------------------------------------------------------------------
// Hierarchical exclusive scan of degpack -> rowptr[N+1]
// ---------------------------------------------------------------------------
__global__ __launch_bounds__(256) void scan1_kernel(const u32* __restrict__ degpack,
                                                    int* __restrict__ rowptr,
                                                    int* __restrict__ blk_sums) {
    __shared__ int sh[256];
    const int t = threadIdx.x;
    const int base = blockIdx.x * 512;
    const int i0 = base + 2 * t, i1 = i0 + 1;
    int d0 = 0, d1 = 0;
    if (i0 < N_NODES) {
        u32 v = degpack[i0 >> 1];
        d0 = (int)(v & 0xFFFFu);
        d1 = (int)(v >> 16);
    }
    const int pair = d0 + d1;
    int v = pair;
    sh[t] = v;
    __syncthreads();
#pragma unroll
    for (int off = 1; off < 256; off <<= 1) {
        int add = (t >= off) ? sh[t - off] : 0;
        __syncthreads();
        v += add;
        sh[t] = v;
        __syncthreads();
    }
    const int excl = v - pair;
    if (i0 < N_NODES) rowptr[i0] = excl;
    if (i1 < N_NODES) rowptr[i1] = excl + d0;
    if (t == 255) blk_sums[blockIdx.x] = v;
}

__global__ __launch_bounds__(128) void scan2_kernel(const int* __restrict__ blk_sums,
                                                    int* __restrict__ blk_offs,
                                                    int* __restrict__ rowptr) {
    __shared__ int sh[128];
    const int t = threadIdx.x;
    const int orig = (t < SCAN_NB) ? blk_sums[t] : 0;
    int v = orig;
    sh[t] = v;
    __syncthreads();
#pragma unroll
    for (int off = 1; off < 128; off <<= 1) {
        int add = (t >= off) ? sh[t - off] : 0;
        __syncthreads();
        v += add;
        sh[t] = v;
        __syncthreads();
    }
    if (t < SCAN_NB) blk_offs[t] = v - orig;
    if (t == 127) rowptr[N_NODES] = v;
}

__global__ void scan3_kernel(int* __restrict__ rowptr,
                             const int* __restrict__ blk_offs) {
    int i = blockIdx.x * blockDim.x + threadIdx.x;
    if (i >= N_NODES) return;
    rowptr[i] += blk_offs[i >> 9];
}

// ---------------------------------------------------------------------------
// CSR placement, NO global atomics (counting sort). NPASS=4 (50KB lcur) halves
// the redundant dst16 scan passes vs NPASS=8; per-line csr writer-sharing is
// per-chunk either way, so write behavior is unchanged.
// ---------------------------------------------------------------------------
__global__ __launch_bounds__(256) void place_kernel(const int* __restrict__ edge_index,
                                                    const float* __restrict__ ew,
                                                    const u16* __restrict__ dst16,
                                                    const int* __restrict__ rowptr,
                                                    const u32* __restrict__ prefpack,
                                                    int2* __restrict__ csr) {
    __shared__ int lcur[NODES_PER_PASS];
    const int pass = blockIdx.x & (NPASS - 1);
    const int c = blockIdx.x >> 2;
    const int lo = pass * NODES_PER_PASS;
    const int t = threadIdx.x;
    for (int i = t; i < NODES_PER_PASS; i += 256) lcur[i] = 0;
    __syncthreads();
    const int base = c * EDGES_PER_CHUNK;
    for (int i = t; i < EDGES_PER_CHUNK; i += 256) {
        const int e = base + i;
        const int d = (int)dst16[e];
        const int dl = d - lo;
        if ((unsigned)dl < (unsigned)NODES_PER_PASS) {
            u32 pw = prefpack[(size_t)c * 25000 + (d >> 1)];
            int pref = (int)((pw >> ((d & 1) * 16)) & 0xFFFFu);
            int lpos = atomicAdd(&lcur[dl], 1);
            int2 ent;
            ent.x = edge_index[e];
            ent.y = __float_as_int(ew[e]);
            csr[rowptr[d] + pref + lpos] = ent;
        }
    }
}

// ---------------------------------------------------------------------------
// FUSED gather + GEMM, layer 0. Block = 1024 threads (16 waves) owns 64 nodes.
// Phase A: wave w gathers nodes w*4..w*4+3 (s = sum w_e x_src, c = sum w_e),
//          staging A = [h | s | c*h] (K=192) in LDS. Stride 200 bf16 = 400B
//          = 100 words = 4 mod 32 banks -> 2-way conflict (free).
// Phase B: h1 = elu(A @ Bp0 + b3 + c*b1); 16 waves = 4x4 grid of 16x16 tiles.
// Kills the sb/chb HBM round-trip and one launch.
// ---------------------------------------------------------------------------
__global__ __launch_bounds__(1024) void fused_l0(
    const u16* __restrict__ xb, const int* __restrict__ rowptr,
    const int2* __restrict__ csr, const u16* __restrict__ Bp0,
    const float* __restrict__ bias1, const float* __restrict__ bias3,
    float* __restrict__ cvec, u16* __restrict__ h1out) {
    __shared__ u16 A[64][200];
    __shared__ float csh[64];
    const int tid = threadIdx.x;
    const int wv = tid >> 6;
    const int lane = tid & 63;
    const int node_base = blockIdx.x * 64;
    const uint2* x2 = (const uint2*)xb;
    const int cg = lane & 15;
    const int eg = lane >> 4;

    // ---- phase A: gather 4 nodes per wave
    for (int k = 0; k < 4; k++) {
        const int row = wv * 4 + k;
        const int node = node_base + row;
        float a0 = 0.f, a1 = 0.f, a2 = 0.f, a3 = 0.f;
        float b0 = 0.f, b1 = 0.f, b2 = 0.f, b3 = 0.f;
        float wsum = 0.f;
        if (node < N_NODES) {
            const int beg = rowptr[node];
            const int end = rowptr[node + 1];
            int p = beg + eg;
            for (; p + 4 < end; p += 8) {
                int2 e0 = csr[p];
                int2 e1 = csr[p + 4];
                float w0 = __int_as_float(e0.y);
                float w1 = __int_as_float(e1.y);
                uint2 v0 = x2[(size_t)e0.x * 16 + cg];
                uint2 v1 = x2[(size_t)e1.x * 16 + cg];
                float f0, f1, f2, f3, g0, g1, g2, g3;
                bfpair(v0.x, f0, f1); bfpair(v0.y, f2, f3);
                bfpair(v1.x, g0, g1); bfpair(v1.y, g2, g3);
                a0 += w0 * f0; a1 += w0 * f1; a2 += w0 * f2; a3 += w0 * f3;
                b0 += w1 * g0; b1 += w1 * g1; b2 += w1 * g2; b3 += w1 * g3;
                wsum += w0 + w1;
            }
            if (p < end) {
                int2 e0 = csr[p];
                float w0 = __int_as_float(e0.y);
                uint2 v0 = x2[(size_t)e0.x * 16 + cg];
                float f0, f1, f2, f3;
                bfpair(v0.x, f0, f1); bfpair(v0.y, f2, f3);
                a0 += w0 * f0; a1 += w0 * f1; a2 += w0 * f2; a3 += w0 * f3;
                wsum += w0;
            }
        }
        a0 += b0; a1 += b1; a2 += b2; a3 += b3;
#pragma unroll
        for (int off = 32; off >= 16; off >>= 1) {
            a0 += __shfl_xor(a0, off);
            a1 += __shfl_xor(a1, off);
            a2 += __shfl_xor(a2, off);
            a3 += __shfl_xor(a3, off);
            wsum += __shfl_xor(wsum, off);
        }
        if (lane < 16) {
            const float cn = wsum;
            uint2 hv = (node < N_NODES) ? x2[(size_t)node * 16 + cg] : (uint2){0u, 0u};
            uint2 so;
            so.x = packbf(a0, a1);
            so.y = packbf(a2, a3);
            *(uint2*)&A[row][cg * 4] = hv;
            *(uint2*)&A[row][64 + cg * 4] = so;
            float h0, h1f, h2f, h3f;
            bfpair(hv.x, h0, h1f); bfpair(hv.y, h2f, h3f);
            uint2 co;
            co.x = packbf(cn * h0, cn * h1f);
            co.y = packbf(cn * h2f, cn * h3f);
            *(uint2*)&A[row][128 + cg * 4] = co;
            if (cg == 0) {
                csh[row] = cn;
                if (node < N_NODES) cvec[node] = cn;
            }
        }
    }
    __syncthreads();

    // ---- phase B: 64x64 GEMM, K=192
    const int l15 = lane & 15;
    const int q = lane >> 4;
    const int qo = q * 8;
    const int mt = wv >> 2, nt = wv & 3;
    f32x4 acc = {0.f, 0.f, 0.f, 0.f};
#pragma unroll
    for (int chunk = 0; chunk < 6; chunk++) {
        bf16x8 a = *(const bf16x8*)&A[mt * 16 + l15][chunk * 32 + qo];
        bf16x8 b = *(const bf16x8*)(Bp0 + (((size_t)(chunk * 4 + nt) * 64 + lane) << 3));
        acc = __builtin_amdgcn_mfma_f32_16x16x32_bf16(a, b, acc, 0, 0, 0);
    }
    const int col = nt * 16 + l15;
    const float B3 = bias3[col];
    const float B1 = bias1[col];
#pragma unroll
    for (int reg = 0; reg < 4; reg++) {
        const int lrow = mt * 16 + q * 4 + reg;
        const int row = node_base + lrow;
        if (row < N_NODES) {
            const float val = acc[reg] + B3 + csh[lrow] * B1;
            h1out[(size_t)row * 64 + col] = f2bf(elu_f(val));
        }
    }
}

// ---------------------------------------------------------------------------
// FUSED gather + GEMM1 + wide GEMM2, layer 1 (+ layer-2 pre-GEMM).
// Phase A: gather on h1 (c recomputed, bitwise-identical order to L0).
// Phase B: ht = elu(A @ Bp1 + b3 + c*b1)  (64x128, K=192, LDS [64][136]).
// Phase C: zuy = ht @ Bp2                 (64x192, K=128).
// ---------------------------------------------------------------------------
__global__ __launch_bounds__(1024) void fused_l1(
    const u16* __restrict__ h1in, const int* __restrict__ rowptr,
    const int2* __restrict__ csr, const u16* __restrict__ Bp1,
    const u16* __restrict__ Bp2, const float* __restrict__ bias1,
    const float* __restrict__ bias3, u16* __restrict__ zuy) {
    __shared__ u16 A[64][200];
    __shared__ u16 ht[64][136];
    __shared__ float csh[64];
    const int tid = threadIdx.x;
    const int wv = tid >> 6;
    const int lane = tid & 63;
    const int node_base = blockIdx.x * 64;
    const uint2* x2 = (const uint2*)h1in;
    const int cg = lane & 15;
    const int eg = lane >> 4;

    // ---- phase A
    for (int k = 0; k < 4; k++) {
        const int row = wv * 4 + k;
        const int node = node_base + row;
        float a0 = 0.f, a1 = 0.f, a2 = 0.f, a3 = 0.f;
        float b0 = 0.f, b1 = 0.f, b2 = 0.f, b3 = 0.f;
        float wsum = 0.f;
        if (node < N_NODES) {
            const int beg = rowptr[node];
            const int end = rowptr[node + 1];
            int p = beg + eg;
            for (; p + 4 < end; p += 8) {
                int2 e0 = csr[p];
                int2 e1 = csr[p + 4];
                float w0 = __int_as_float(e0.y);
                float w1 = __int_as_float(e1.y);
                uint2 v0 = x2[(size_t)e0.x * 16 + cg];
                uint2 v1 = x2[(size_t)e1.x * 16 + cg];
                float f0, f1, f2, f3, g0, g1, g2, g3;
                bfpair(v0.x, f0, f1); bfpair(v0.y, f2, f3);
                bfpair(v1.x, g0, g1); bfpair(v1.y, g2, g3);
                a0 += w0 * f0; a1 += w0 * f1; a2 += w0 * f2; a3 += w0 * f3;
                b0 += w1 * g0; b1 += w1 * g1; b2 += w1 * g2; b3 += w1 * g3;
                wsum += w0 + w1;
            }
            if (p < end) {
                int2 e0 = csr[p];
                float w0 = __int_as_float(e0.y);
                uint2 v0 = x2[(size_t)e0.x * 16 + cg];
                float f0, f1, f2, f3;
                bfpair(v0.x, f0, f1); bfpair(v0.y, f2, f3);
                a0 += w0 * f0; a1 += w0 * f1; a2 += w0 * f2; a3 += w0 * f3;
                wsum += w0;
            }
        }
        a0 += b0; a1 += b1; a2 += b2; a3 += b3;
#pragma unroll
        for (int off = 32; off >= 16; off >>= 1) {
            a0 += __shfl_xor(a0, off);
            a1 += __shfl_xor(a1, off);
            a2 += __shfl_xor(a2, off);
            a3 += __shfl_xor(a3, off);
            wsum += __shfl_xor(wsum, off);
        }
        if (lane < 16) {
            const float cn = wsum;
            uint2 hv = (node < N_NODES) ? x2[(size_t)node * 16 + cg] : (uint2){0u, 0u};
            uint2 so;
            so.x = packbf(a0, a1);
            so.y = packbf(a2, a3);
            *(uint2*)&A[row][cg * 4] = hv;
            *(uint2*)&A[row][64 + cg * 4] = so;
            float h0, h1f, h2f, h3f;
            bfpair(hv.x, h0, h1f); bfpair(hv.y, h2f, h3f);
            uint2 co;
            co.x = packbf(cn * h0, cn * h1f);
            co.y = packbf(cn * h2f, cn * h3f);
            *(uint2*)&A[row][128 + cg * 4] = co;
            if (cg == 0) csh[row] = cn;
        }
    }
    __syncthreads();

    const int l15 = lane & 15;
    const int q = lane >> 4;
    const int qo = q * 8;

    // ---- phase B: 64x128 GEMM, K=192, epilogue to LDS ht
    {
        const int mt = wv >> 2;
        const int nt0 = (wv & 3) * 2;
        f32x4 acc0 = {0.f, 0.f, 0.f, 0.f};
        f32x4 acc1 = {0.f, 0.f, 0.f, 0.f};
#pragma unroll
        for (int chunk = 0; chunk < 6; chunk++) {
            bf16x8 a = *(const bf16x8*)&A[mt * 16 + l15][chunk * 32 + qo];
            bf16x8 bf0 = *(const bf16x8*)(Bp1 + (((size_t)(chunk * 8 + nt0) * 64 + lane) << 3));
            bf16x8 bf1 = *(const bf16x8*)(Bp1 + (((size_t)(chunk * 8 + nt0 + 1) * 64 + lane) << 3));
            acc0 = __builtin_amdgcn_mfma_f32_16x16x32_bf16(a, bf0, acc0, 0, 0, 0);
            acc1 = __builtin_amdgcn_mfma_f32_16x16x32_bf16(a, bf1, acc1, 0, 0, 0);
        }
#pragma unroll
        for (int ni = 0; ni < 2; ni++) {
            const int col = (nt0 + ni) * 16 + l15;
            const float B3 = bias3[col];
            const float B1 = bias1[col];
            const f32x4 av = ni ? acc1 : acc0;
#pragma unroll
            for (int reg = 0; reg < 4; reg++) {
                const int lrow = mt * 16 + q * 4 + reg;
                ht[lrow][col] = f2bf(elu_f(av[reg] + B3 + csh[lrow] * B1));
            }
        }
    }
    __syncthreads();

    // ---- phase C: 64x192 GEMM, K=128 from ht
    {
        const int mt = wv >> 2;
        const int ntb = (wv & 3) * 3;
        f32x4 acc[3] = {};
#pragma unroll
        for (int chunk = 0; chunk < 4; chunk++) {
            bf16x8 a = *(const bf16x8*)&ht[mt * 16 + l15][chunk * 32 + qo];
#pragma unroll
            for (int j = 0; j < 3; j++) {
                bf16x8 b = *(const bf16x8*)(Bp2 + (((size_t)(chunk * 12 + ntb + j) * 64 + lane) << 3));
                acc[j] = __builtin_amdgcn_mfma_f32_16x16x32_bf16(a, b, acc[j], 0, 0, 0);
            }
        }
#pragma unroll
        for (int j = 0; j < 3; j++) {
            const int col = (ntb + j) * 16 + l15;
#pragma unroll
            for (int reg = 0; reg < 4; reg++) {
                const int row = node_base + mt * 16 + q * 4 + reg;
                if (row < N_NODES)
                    zuy[(size_t)row * 192 + col] = f2bf(acc[j][reg]);
            }
        }
    }
}

// ---------------------------------------------------------------------------
// Layer-2 gather + fused epilogue. zuy rows: [z(64) | u(64) | y(64)].
// h3[i] = elu( z_i + c_i*u_i + sum_e w_e * y[src_e] + b3 + c_i*b1 )
// ---------------------------------------------------------------------------
__global__ __launch_bounds__(256) void gather2_kernel(
    const u16* __restrict__ zuy, const int* __restrict__ rowptr,
    const int2* __restrict__ csr, const float* __restrict__ c,
    const float* __restrict__ bias1, const float* __restrict__ bias3,
    u16* __restrict__ h3) {
    constexpr int CG = 16, EG = 4;
    const int gid = blockIdx.x * 256 + threadIdx.x;
    const int node = gid >> 6;
    if (node >= N_NODES) return;
    const int lane = threadIdx.x & 63;
    const int cg = lane & (CG - 1);
    const int eg = lane >> 4;
    const int beg = rowptr[node];
    const int end = rowptr[node + 1];

    float a0 = 0.f, a1 = 0.f, a2 = 0.f, a3 = 0.f;
    float b0 = 0.f, b1 = 0.f, b2 = 0.f, b3 = 0.f;

    int p = beg + eg;
    for (; p + EG < end; p += 2 * EG) {
        int2 e0 = csr[p];
        int2 e1 = csr[p + EG];
        float w0 = __int_as_float(e0.y);
        float w1 = __int_as_float(e1.y);
        uint2 v0 = ((const uint2*)(zuy + (size_t)e0.x * 192 + 128))[cg];
        uint2 v1 = ((const uint2*)(zuy + (size_t)e1.x * 192 + 128))[cg];
        float f0, f1, f2, f3, g0, g1, g2, g3;
        bfpair(v0.x, f0, f1); bfpair(v0.y, f2, f3);
        bfpair(v1.x, g0, g1); bfpair(v1.y, g2, g3);
        a0 += w0 * f0; a1 += w0 * f1; a2 += w0 * f2; a3 += w0 * f3;
        b0 += w1 * g0; b1 += w1 * g1; b2 += w1 * g2; b3 += w1 * g3;
    }
    if (p < end) {
        int2 e0 = csr[p];
        float w0 = __int_as_float(e0.y);
        uint2 v0 = ((const uint2*)(zuy + (size_t)e0.x * 192 + 128))[cg];
        float f0, f1, f2, f3;
        bfpair(v0.x, f0, f1); bfpair(v0.y, f2, f3);
        a0 += w0 * f0; a1 += w0 * f1; a2 += w0 * f2; a3 += w0 * f3;
    }
    a0 += b0; a1 += b1; a2 += b2; a3 += b3;

#pragma unroll
    for (int off = 32; off >= CG; off >>= 1) {
        a0 += __shfl_xor(a0, off);
        a1 += __shfl_xor(a1, off);
        a2 += __shfl_xor(a2, off);
        a3 += __shfl_xor(a3, off);
    }

    if (lane < CG) {
        const float cn = c[node];
        const u16* zr = zuy + (size_t)node * 192;
        uint2 zv = ((const uint2*)zr)[cg];
        uint2 uv = ((const uint2*)(zr + 64))[cg];
        float z0, z1, z2, z3, u0, u1, u2, u3;
        bfpair(zv.x, z0, z1); bfpair(zv.y, z2, z3);
        bfpair(uv.x, u0, u1); bfpair(uv.y, u2, u3);
        const float4 b3v = *(const float4*)(bias3 + cg * 4);
        const float4 b1v = *(const float4*)(bias1 + cg * 4);
        float o0 = elu_f(z0 + cn * u0 + a0 + b3v.x + cn * b1v.x);
        float o1 = elu_f(z1 + cn * u1 + a1 + b3v.y + cn * b1v.y);
        float o2 = elu_f(z2 + cn * u2 + a2 + b3v.z + cn * b1v.z);
        float o3 = elu_f(z3 + cn * u3 + a3 + b3v.w + cn * b1v.w);
        uint2 o;
        o.x = packbf(o0, o1);
        o.y = packbf(o2, o3);
        ((uint2*)h3)[(size_t)node * CG + cg] = o;
    }
}

// ---------------------------------------------------------------------------
// out[g, :] = max over nodes of graph g of h[:, :64] (bf16 in, fp32 out)
// ---------------------------------------------------------------------------
__global__ void pool_kernel(const u16* __restrict__ h,
                            const int* __restrict__ batch,
                            float* __restrict__ out) {
    const int g = blockIdx.x;
    const int tid = threadIdx.x;
    int lo = 0, hi = N_NODES;
    while (lo < hi) { int mid = (lo + hi) >> 1; if (batch[mid] < g) lo = mid + 1; else hi = mid; }
    const int beg = lo;
    lo = beg; hi = N_NODES;
    while (lo < hi) { int mid = (lo + hi) >> 1; if (batch[mid] < g + 1) lo = mid + 1; else hi = mid; }
    const int end = lo;

    __shared__ float red[256];
    const int col = tid & 63;
    const int rg = tid >> 6;
    float m = -3.0e38f;
    for (int r = beg + rg; r < end; r += 4) m = fmaxf(m, bf2f(h[(size_t)r * 64 + col]));
    red[tid] = m;
    __syncthreads();
    if (tid < 64) {
        m = fmaxf(fmaxf(red[tid], red[tid + 64]), fmaxf(red[tid + 128], red[tid + 192]));
        out[g * 64 + tid] = m;
    }
}

extern "C" void kernel_launch(void* const* d_in, const int* in_sizes, int n_in,
                              void* d_out, int out_size, void* d_ws, size_t ws_size,
                              hipStream_t stream) {
    const float* x = (const float*)d_in[0];
    const int* ei = (const int*)d_in[1];
    const float* ea = (const float*)d_in[2];
    const int* batch = (const int*)d_in[3];
    const float* wfc = (const float*)d_in[4];
    const float* bfc = (const float*)d_in[5];
    const float* w1_0 = (const float*)d_in[6];
    const float* b1_0 = (const float*)d_in[7];
    const float* w2_0 = (const float*)d_in[8];
    const float* w3_0 = (const float*)d_in[9];
    const float* b3_0 = (const float*)d_in[10];
    const float* w1_1 = (const float*)d_in[11];
    const float* b1_1 = (const float*)d_in[12];
    const float* w2_1 = (const float*)d_in[13];
    const float* w3_1 = (const float*)d_in[14];
    const float* b3_1 = (const float*)d_in[15];
    const float* w1_2 = (const float*)d_in[16];
    const float* b1_2 = (const float*)d_in[17];
    const float* w2_2 = (const float*)d_in[18];
    const float* w3_2 = (const float*)d_in[19];
    const float* b3_2 = (const float*)d_in[20];
    float* out = (float*)d_out;

    char* ws = (char*)d_ws;
    float* ew      = (float*)(ws);                 // E f32      3.2 MB
    float* c       = (float*)(ws + 3200000);       // N f32
    int*   rowptr  = (int*)  (ws + 3800000);       // N+1 int
    int2*  csr     = (int2*) (ws + 4000128);       // E int2     6.4 MB
    u16*   xb      = (u16*)  (ws + 10400128);      // N*64 bf16  6.4 MB
    u32*   partial = (u32*)  (ws + 16800128);      // 256*12500 u32 = 12.8 MB
    u16*   dst16   = (u16*)  (ws + 29600128);      // E u16      1.6 MB
    u32*   degpack = (u32*)  (ws + 31600128);      // 100 KB
    u16*   h1      = (u16*)  (ws + 42400128);      // N*64 bf16  6.4 MB
    u16*   zuy     = (u16*)  (ws + 48800128);      // N*192 bf16 19.2 MB
    u16*   bp0     = (u16*)  (ws + 68000128);      // 24 KB packed weights L0
    u16*   bp1     = (u16*)  (ws + 68024704);      // 48 KB L1
    u16*   bp2     = (u16*)  (ws + 68073856);      // 48 KB L2 wide
    int* blk_sums  = (int*)  (ws + 68123008);
    int* blk_offs  = (int*)  (ws + 68123520);
    // aliases into regions dead at time of use:
    u32* prefpack = (u32*)zuy;  // 12.8 MB, dead before fused_l1 writes zuy
    u16* h3 = xb;               // N*64 bf16 (xb dead after fused_l0 phase A)

    // fused prep: ew + conv_x + pack_w in one launch
    prep_kernel<<<6280, 256, 0, stream>>>(ea, wfc, bfc, ei, ew, dst16, x, xb,
                                          w3_0, w1_0, w2_0, w3_1, w1_1, w2_1,
                                          w3_2, w1_2, w2_2, bp0, bp1, bp2);
    deg_hist_kernel<<<HCHUNKS * 2, 256, 0, stream>>>(dst16, partial);
    scan_chunks_kernel<<<TS_BPH * 2, 256, 0, stream>>>(partial, prefpack, degpack);
    scan1_kernel<<<SCAN_NB, 256, 0, stream>>>(degpack, rowptr, blk_sums);
    scan2_kernel<<<1, 128, 0, stream>>>(blk_sums, blk_offs, rowptr);
    scan3_kernel<<<(N_NODES + 255) / 256, 256, 0, stream>>>(rowptr, blk_offs);
    place_kernel<<<HCHUNKS * NPASS, 256, 0, stream>>>(ei, ew, dst16, rowptr, prefpack, csr);

    const int RB = (N_NODES + 63) / 64;           // 782 row-blocks
    const int GBLK = (N_NODES * 64 + 255) / 256;  // one wave per node

    // layer 0: fused gather + GEMM (sb/chb never touch HBM)
    fused_l0<<<RB, 1024, 0, stream>>>(xb, rowptr, csr, bp0, b1_0, b3_0, c, h1);

    // layer 1 + layer-2 wide GEMM: fused gather + GEMM1 + GEMM2
    fused_l1<<<RB, 1024, 0, stream>>>(h1, rowptr, csr, bp1, bp2, b1_1, b3_1, zuy);

    // layer 2 gather in output space + fused epilogue
    gather2_kernel<<<GBLK, 256, 0, stream>>>(zuy, rowptr, csr, c, b1_2, b3_2, h3);

    // global max pool
    pool_kernel<<<NUM_GRAPHS_, 256, 0, stream>>>(h3, batch, out);
}